// Round 6
// baseline (300.833 us; speedup 1.0000x reference)
//
#include <hip/hip_runtime.h>
#include <hip/hip_bf16.h>

#define GAMMA 0.25f

// Shapes: B=1024, C=3, H=64, D=256, NP=64 (8x8 grid of 8x8 patches),
//         M=1024, NH=8, R=32, P=8.  fp32 in/out.  out[b] = quad - coupling.
//
// R6: k_mega2.  R5 counters: 2.49M LDS bank conflicts (frag-ordered zf
// stores: all lanes -> 2 banks) and 2 blocks/CU occupancy wall (64KB LDS).
//  - zs is now row-major [64][256] bf16 with XOR swizzle (ba ^= ((row&7)<<4)):
//    conflict-free writes (row const/wave) and bank-optimal b128 frag reads.
//  - attn runs as 4 head-pair iterations; dstg = [64][128] (16KB).  LDS
//    48KB -> 3 blocks/CU (12 waves), __launch_bounds__(256,3).
//  - mem phase first (barrier-free), z read exactly once per b.

typedef __attribute__((ext_vector_type(8))) short short8;  // 8 bf16 (4 VGPRs)
typedef __attribute__((ext_vector_type(4))) float f32x4;   // 4 fp32 acc

// byte-addr XOR swizzles (bits 4-6 only: preserves 16B read units)
#define ZS_SWZ(a) ((a) ^ ((((a) >> 9) & 7) << 4))  // zs rows = 512B
#define DG_SWZ(a) ((a) ^ ((((a) >> 8) & 7) << 4))  // dstg rows = 256B

__device__ __forceinline__ float dot4(float4 a, float4 b) {
  return fmaf(a.x, b.x, fmaf(a.y, b.y, fmaf(a.z, b.z, a.w * b.w)));
}

__device__ __forceinline__ void fma4(float4& a, float s, float4 w) {
  a.x = fmaf(s, w.x, a.x); a.y = fmaf(s, w.y, a.y);
  a.z = fmaf(s, w.z, a.z); a.w = fmaf(s, w.w, a.w);
}

__device__ __forceinline__ ushort f2bf(float f) {
  __hip_bfloat16 h = __float2bfloat16(f);  // RNE
  return *reinterpret_cast<ushort*>(&h);
}

__device__ __forceinline__ float bf2f(ushort u) {
  union { unsigned int i; float f; } v;
  v.i = ((unsigned int)u) << 16;
  return v.f;
}

// A-fragment read from swizzled row-major zs: rows 16*rt+(l&15),
// cols kc*32+(l>>4)*8 .. +7  (bf16).
__device__ __forceinline__ short8 zs_frag(const char* zsb, int rt, int kc,
                                          int l) {
  int row = 16 * rt + (l & 15);
  int ba = row * 512 + (kc * 32 + (l >> 4) * 8) * 2;
  return *(const short8*)(zsb + ZS_SWZ(ba));
}

// 256-thread block sum; result valid on all threads.
__device__ __forceinline__ float block_sum_256(float v, float* tmp) {
#pragma unroll
  for (int off = 32; off; off >>= 1) v += __shfl_down(v, off, 64);
  int w = threadIdx.x >> 6;
  if ((threadIdx.x & 63) == 0) tmp[w] = v;
  __syncthreads();
  return tmp[0] + tmp[1] + tmp[2] + tmp[3];
}

// ---------------------------------------------------------------------------
// Weight conversion, fragment-linear (one launch, block ranges):
// [0,64)   wcf: frag=ctg*8+kc (ctg 0..31): Wcat cols [h][qk][rr], 256 frags
// [64,88)  ewt: frag=ks*12+ct: B[d][kcol]=ew[d*192+kcol]   96 frags
// [88,216) mtf: frag=C*8+kc:   B[k][m]=mw[k][C*16+m]      512 frags
// Each fragment = contiguous [l][8] 1KB wave-block.
// ---------------------------------------------------------------------------
__global__ __launch_bounds__(256) void k_cvt_weights_v4(
    const float* __restrict__ wq, const float* __restrict__ wk,
    const float* __restrict__ ew, const float* __restrict__ mw,
    ushort* __restrict__ wcf, ushort* __restrict__ ewt,
    ushort* __restrict__ mtf) {
  int bid = blockIdx.x, t = threadIdx.x;
  ushort o[8];
  if (bid < 64) {
    int tid = bid * 256 + t;  // 0..16383
    int frag = tid >> 6, l = tid & 63;
    int ctg = frag >> 3, kc = frag & 7;
    int col = ctg * 16 + (l & 15);
    int h = col >> 6, qk = (col >> 5) & 1, rr = col & 31;
    int k0 = kc * 32 + (l >> 4) * 8;
    const float* s = (qk ? wk : wq) + ((size_t)h * 32 + rr) * 256 + k0;
#pragma unroll
    for (int i = 0; i < 8; ++i) o[i] = f2bf(s[i]);
    *(ushort4*)(wcf + (size_t)tid * 8) = *(ushort4*)&o[0];
    *(ushort4*)(wcf + (size_t)tid * 8 + 4) = *(ushort4*)&o[4];
  } else if (bid < 88) {
    int tid = (bid - 64) * 256 + t;  // 0..6143
    int frag = tid >> 6, l = tid & 63;
    int ks = frag / 12, ct = frag % 12;
    const float* s = ew + (size_t)(ks * 32 + (l >> 4) * 8) * 192 +
                     ct * 16 + (l & 15);
#pragma unroll
    for (int i = 0; i < 8; ++i) o[i] = f2bf(s[(size_t)i * 192]);
    *(ushort4*)(ewt + (size_t)tid * 8) = *(ushort4*)&o[0];
    *(ushort4*)(ewt + (size_t)tid * 8 + 4) = *(ushort4*)&o[4];
  } else {
    int tid = (bid - 88) * 256 + t;  // 0..32767
    int frag = tid >> 6, l = tid & 63;
    int C = frag >> 3, kc = frag & 7;
    int k0 = kc * 32 + (l >> 4) * 8, col = C * 16 + (l & 15);
#pragma unroll
    for (int i = 0; i < 8; ++i) o[i] = f2bf(mw[(size_t)(k0 + i) * 1024 + col]);
    *(ushort4*)(mtf + (size_t)tid * 8) = *(ushort4*)&o[0];
    *(ushort4*)(mtf + (size_t)tid * 8 + 4) = *(ushort4*)&o[4];
  }
}

// ---------------------------------------------------------------------------
// Mega-kernel v2: quad_z - phi_bias - phi_pos - phi_mem - phi_att, per b.
// LDS 48KB: zs = swizzled row-major [64][256] bf16 (32KB), dstg = swizzled
// [64][128] bf16 head-pair Q|K tile (16KB).  3 blocks/CU.
// ---------------------------------------------------------------------------
__global__ __launch_bounds__(256, 3) void k_mega2(
    const float* __restrict__ z, const float* __restrict__ eb,
    const float* __restrict__ pb, const ushort* __restrict__ mtf,
    const ushort* __restrict__ wcf, float* __restrict__ out) {
  __shared__ char SL[49152];  // 48 KB
  __shared__ float tmp[4];
  char* zsb = SL;           // 32 KB
  char* dgb = SL + 32768;   // 16 KB
  const int t = threadIdx.x, l = t & 63, w = t >> 6;
  const int b = blockIdx.x;
  const int q = l >> 4, m = l & 15;
  float s = 0.f;

  // ---- Phase 0: z fp32 coalesced -> quad_z - phi_bias - phi_pos; zs (bf16).
  // p = i>>6 is const per wave -> swizzle XOR const -> conflict-free writes.
  {
    const float4* zb4 = (const float4*)(z + (size_t)b * 16384);
    const float4* pb4 = (const float4*)pb;
    const float4* eb4 = (const float4*)eb;
#pragma unroll
    for (int n = 0; n < 16; ++n) {
      int i = t + n * 256;
      float4 zv = zb4[i];
      float4 pv = pb4[i];
      float4 ev = eb4[i & 63];
      float4 c;
      c.x = pv.x + ev.x; c.y = pv.y + ev.y;
      c.z = pv.z + ev.z; c.w = pv.w + ev.w;
      s += 0.5f * dot4(zv, zv) - dot4(zv, c);
      int p = i >> 6, d4 = i & 63;
      int ba = p * 512 + d4 * 8;
      ushort4 o;
      o.x = f2bf(zv.x); o.y = f2bf(zv.y); o.z = f2bf(zv.z); o.w = f2bf(zv.w);
      *(ushort4*)(zsb + ZS_SWZ(ba)) = o;
    }
  }
  __syncthreads();

  // ---- Phase 1: phi_mem (4 ct chunks, barrier-free; B from L2 mtf).
#pragma unroll 1
  for (int ct = 0; ct < 4; ++ct) {
    const ushort* Bb = mtf + ((size_t)(ct * 16 + w * 4) * 8) * 512 +
                       (size_t)l * 8;
    short8 fb[2][4];
#pragma unroll
    for (int c = 0; c < 4; ++c) fb[0][c] = *(const short8*)(Bb + (c * 8 + 0) * 512);
#pragma unroll
    for (int c = 0; c < 4; ++c) fb[1][c] = *(const short8*)(Bb + (c * 8 + 1) * 512);

    f32x4 acc[4][4];
#pragma unroll
    for (int r = 0; r < 4; ++r)
#pragma unroll
      for (int c = 0; c < 4; ++c) acc[r][c] = f32x4{0.f, 0.f, 0.f, 0.f};

#pragma unroll
    for (int kc = 0; kc < 8; ++kc) {
      const int cur = kc & 1;
      short8 a4[4];
#pragma unroll
      for (int r = 0; r < 4; ++r) a4[r] = zs_frag(zsb, r, kc, l);
#pragma unroll
      for (int r = 0; r < 4; ++r)
#pragma unroll
        for (int c = 0; c < 4; ++c)
          acc[r][c] = __builtin_amdgcn_mfma_f32_16x16x32_bf16(a4[r], fb[cur][c],
                                                              acc[r][c], 0, 0, 0);
      if (kc < 6) {
#pragma unroll
        for (int c = 0; c < 4; ++c)
          fb[cur][c] = *(const short8*)(Bb + (c * 8 + kc + 2) * 512);
      }
    }
#pragma unroll
    for (int r = 0; r < 4; ++r)
#pragma unroll
      for (int c = 0; c < 4; ++c)
#pragma unroll
        for (int e = 0; e < 4; ++e) {
          float rr = fmaxf(acc[r][c][e], 0.f);
          s -= rr * rr;
        }
  }

  // ---- Phase 2: phi_att, 4 head-pair iterations (heads 2hp, 2hp+1).
  float part = 0.f;
#pragma unroll 1
  for (int hp = 0; hp < 4; ++hp) {
    // wave w owns col-tile group ctg = hp*8 + w*2 + c (c in 0..1).
    const ushort* Bb = wcf + ((size_t)((hp * 8 + w * 2) * 8)) * 512 +
                       (size_t)l * 8;
    short8 fb[2][2];
#pragma unroll
    for (int c = 0; c < 2; ++c) fb[0][c] = *(const short8*)(Bb + (c * 8 + 0) * 512);
#pragma unroll
    for (int c = 0; c < 2; ++c) fb[1][c] = *(const short8*)(Bb + (c * 8 + 1) * 512);

    f32x4 acc[4][2];
#pragma unroll
    for (int r = 0; r < 4; ++r)
#pragma unroll
      for (int c = 0; c < 2; ++c) acc[r][c] = f32x4{0.f, 0.f, 0.f, 0.f};

#pragma unroll
    for (int kc = 0; kc < 8; ++kc) {
      const int cur = kc & 1;
      short8 a4[4];
#pragma unroll
      for (int r = 0; r < 4; ++r) a4[r] = zs_frag(zsb, r, kc, l);
#pragma unroll
      for (int r = 0; r < 4; ++r)
#pragma unroll
        for (int c = 0; c < 2; ++c)
          acc[r][c] = __builtin_amdgcn_mfma_f32_16x16x32_bf16(a4[r], fb[cur][c],
                                                              acc[r][c], 0, 0, 0);
      if (kc < 6) {
#pragma unroll
        for (int c = 0; c < 2; ++c)
          fb[cur][c] = *(const short8*)(Bb + (c * 8 + kc + 2) * 512);
      }
    }

    // Store D (row = 16rt+4q+reg, local col lc = (2w+c)*16+m) -> dstg.
#pragma unroll
    for (int rt = 0; rt < 4; ++rt)
#pragma unroll
      for (int c = 0; c < 2; ++c)
#pragma unroll
        for (int reg = 0; reg < 4; ++reg) {
          int row = 16 * rt + 4 * q + reg;
          int lc = (2 * w + c) * 16 + m;
          int ba = row * 256 + lc * 2;
          *(ushort*)(dgb + DG_SWZ(ba)) = f2bf(acc[rt][c][reg]);
        }
    __syncthreads();

    // QK^T + lse for the two heads (Q cols hh*64.., K cols hh*64+32..).
#pragma unroll
    for (int hh = 0; hh < 2; ++hh) {
      int rowq = 16 * w + m;
      short8 qa = *(const short8*)(
          dgb + DG_SWZ(rowq * 256 + (hh * 64 + q * 8) * 2));
      f32x4 a2[4];
#pragma unroll
      for (int nt = 0; nt < 4; ++nt) {
        int rowk = 16 * nt + m;
        a2[nt] = __builtin_amdgcn_mfma_f32_16x16x32_bf16(
            qa,
            *(const short8*)(dgb + DG_SWZ(rowk * 256 + (hh * 64 + 32 + q * 8) * 2)),
            f32x4{0.f, 0.f, 0.f, 0.f}, 0, 0, 0);
      }
#pragma unroll
      for (int reg = 0; reg < 4; ++reg) {
        float e = __expf(GAMMA * a2[0][reg]) + __expf(GAMMA * a2[1][reg]) +
                  __expf(GAMMA * a2[2][reg]) + __expf(GAMMA * a2[3][reg]);
        e += __shfl_xor(e, 1, 64);
        e += __shfl_xor(e, 2, 64);
        e += __shfl_xor(e, 4, 64);
        e += __shfl_xor(e, 8, 64);
        part += (m == 0) ? __logf(e) : 0.f;  // one log per row 16w+4q+reg
      }
    }
    __syncthreads();  // dstg reads done before next pair's writes
  }
  s -= part * (1.0f / GAMMA);

  float r = block_sum_256(s, tmp);
  if (t == 0) out[b] = r;
}

// ---------------------------------------------------------------------------
// Kernel: quad_x - phi_vis - phi_enc (unchanged R5 body).
// ---------------------------------------------------------------------------
__global__ __launch_bounds__(256) void k_enc_v5(
    const float* __restrict__ x, const float* __restrict__ vb,
    const float* __restrict__ z, const ushort* __restrict__ ewt,
    float* __restrict__ out) {
  __shared__ ushort xs[12288];      // 24 KB: x[b] bf16, NCHW layout
  __shared__ ushort ebuf[2][6144];  // 2 x 12 KB: ewt ks-chunk double buffer
  __shared__ float tmp[4];
  const int b = blockIdx.x, t = threadIdx.x, l = t & 63, w = t >> 6;
  const int q = l >> 4, m = l & 15;

  // z A-frags from fp32 (L3-warm after k_mega2); RNE cvt == bf16 path.
  const float* Zr = z + (size_t)b * 16384 + (size_t)(16 * w + m) * 256 + q * 8;
  short8 a[8];
#pragma unroll
  for (int ks = 0; ks < 8; ++ks) {
    float4 u = *(const float4*)(Zr + ks * 32);
    float4 v = *(const float4*)(Zr + ks * 32 + 4);
    ushort o[8];
    o[0] = f2bf(u.x); o[1] = f2bf(u.y); o[2] = f2bf(u.z); o[3] = f2bf(u.w);
    o[4] = f2bf(v.x); o[5] = f2bf(v.y); o[6] = f2bf(v.z); o[7] = f2bf(v.w);
    a[ks] = *(short8*)o;
  }

  // chunk-0 staging loads (in flight during x staging)
  short8 st[3];
#pragma unroll
  for (int i = 0; i < 3; ++i)
    st[i] = *(const short8*)(ewt + (size_t)(t + i * 256) * 8);

  // Stage x -> bf16 LDS; accumulate quad_x - phi_vis.
  const float4* xb = (const float4*)(x + (size_t)b * 12288);
  const float4* vb4 = (const float4*)vb;
  ushort4* xs4 = (ushort4*)xs;
  float s = 0.f;
  for (int i = t; i < 3072; i += 256) {
    float4 xv = xb[i];
    float4 bv = vb4[i];
    s += 0.5f * dot4(xv, xv) - dot4(bv, xv);
    ushort4 o;
    o.x = f2bf(xv.x); o.y = f2bf(xv.y); o.z = f2bf(xv.z); o.w = f2bf(xv.w);
    xs4[i] = o;
  }
#pragma unroll
  for (int i = 0; i < 3; ++i)
    *(short8*)(ebuf[0] + (size_t)(t + i * 256) * 8) = st[i];
  __syncthreads();

  f32x4 acc[12];
#pragma unroll
  for (int ct = 0; ct < 12; ++ct) acc[ct] = f32x4{0.f, 0.f, 0.f, 0.f};

#pragma unroll
  for (int ks = 0; ks < 8; ++ks) {
    const int cur = ks & 1;
    if (ks < 7) {
#pragma unroll
      for (int i = 0; i < 3; ++i)
        st[i] = *(const short8*)(ewt + (size_t)(ks + 1) * 6144 +
                                 (size_t)(t + i * 256) * 8);
    }
#pragma unroll
    for (int ct = 0; ct < 12; ++ct) {
      short8 bv = *(const short8*)(ebuf[cur] + (size_t)(ct * 64 + l) * 8);
      acc[ct] = __builtin_amdgcn_mfma_f32_16x16x32_bf16(a[ks], bv, acc[ct], 0, 0, 0);
    }
    if (ks < 7) {
#pragma unroll
      for (int i = 0; i < 3; ++i)
        *(short8*)(ebuf[cur ^ 1] + (size_t)(t + i * 256) * 8) = st[i];
    }
    __syncthreads();
  }

  // Epilogue: D element (row p=16w+4q+reg, col k=16ct+m) * x[p,k] from LDS.
#pragma unroll
  for (int ct = 0; ct < 12; ++ct) {
#pragma unroll
    for (int reg = 0; reg < 4; ++reg) {
      const int p = 16 * w + 4 * q + reg, gi = p >> 3, gj = p & 7;
      const int k = ct * 16 + m, c = k >> 6, r2 = k & 63;
      const int ii = r2 >> 3, jj = r2 & 7;
      s -= acc[ct][reg] * bf2f(xs[c * 4096 + (gi * 8 + ii) * 64 + gj * 8 + jj]);
    }
  }
  float r = block_sum_256(s, tmp);
  if (t == 0) atomicAdd(out + b, r);  // += quad_x - phi_vis - phi_enc
}

// ---------------------------------------------------------------------------
// Fallback kernels (no-workspace tier).
// ---------------------------------------------------------------------------
__global__ __launch_bounds__(256) void k_xz(const float* __restrict__ x,
                                            const float* __restrict__ z,
                                            const float* __restrict__ vb,
                                            const float* __restrict__ eb,
                                            const float* __restrict__ pb,
                                            float* __restrict__ out) {
  __shared__ float tmp[4];
  int b = blockIdx.x, t = threadIdx.x;
  const float4* xb = (const float4*)(x + (size_t)b * 12288);
  const float4* vb4 = (const float4*)vb;
  float s = 0.f;
  for (int i = t; i < 3072; i += 256) {
    float4 xv = xb[i];
    float4 bv = vb4[i];
    s += 0.5f * dot4(xv, xv) - dot4(bv, xv);
  }
  const float4* zb = (const float4*)(z + (size_t)b * 16384);
  const float4* pb4 = (const float4*)pb;
  const float4* eb4 = (const float4*)eb;
  for (int i = t; i < 4096; i += 256) {
    float4 zv = zb[i];
    float4 pv = pb4[i];
    float4 ev = eb4[i & 63];
    float4 c;
    c.x = pv.x + ev.x; c.y = pv.y + ev.y; c.z = pv.z + ev.z; c.w = pv.w + ev.w;
    s += 0.5f * dot4(zv, zv) - dot4(zv, c);
  }
  float r = block_sum_256(s, tmp);
  if (t == 0) out[b] = r;
}

__global__ __launch_bounds__(256) void k_enc(const float* __restrict__ x,
                                             const float* __restrict__ z,
                                             const float* __restrict__ ew,
                                             float* __restrict__ out) {
  __shared__ float xs[12288];
  __shared__ float tmp[4];
  int b = blockIdx.x, t = threadIdx.x;
  const float4* xb4 = (const float4*)(x + (size_t)b * 12288);
  for (int i = t; i < 3072; i += 256) ((float4*)xs)[i] = xb4[i];
  __syncthreads();

  float acc[64];
#pragma unroll
  for (int p = 0; p < 64; ++p) acc[p] = 0.f;

  for (int k4 = 0; k4 < 48; ++k4) {
    float4 wv = *(const float4*)(ew + (size_t)t * 192 + k4 * 4);
    int c = k4 >> 4;
    int ii = (k4 >> 1) & 7;
    int jh = (k4 & 1) * 4;
    const float* base = xs + c * 4096 + ii * 64 + jh;
#pragma unroll
    for (int p = 0; p < 64; ++p) {
      float4 pv = *(const float4*)(base + (p >> 3) * 512 + (p & 7) * 8);
      acc[p] = fmaf(wv.x, pv.x,
               fmaf(wv.y, pv.y, fmaf(wv.z, pv.z, fmaf(wv.w, pv.w, acc[p]))));
    }
  }
  const float* zb = z + (size_t)b * 16384;
  float s = 0.f;
#pragma unroll
  for (int p = 0; p < 64; ++p) s += acc[p] * zb[p * 256 + t];
  float r = block_sum_256(s, tmp);
  if (t == 0) atomicAdd(out + b, -r);
}

__global__ __launch_bounds__(256) void k_mem(const float* __restrict__ z,
                                             const float* __restrict__ mw,
                                             float* __restrict__ out) {
  __shared__ float zs[16 * 256];
  __shared__ float tmp[4];
  int b = blockIdx.x >> 2, pt = blockIdx.x & 3, t = threadIdx.x;
  const float4* zb4 = (const float4*)(z + (size_t)b * 16384 + pt * 4096);
  for (int i = t; i < 1024; i += 256) ((float4*)zs)[i] = zb4[i];
  __syncthreads();

  const float4* m4 = (const float4*)mw;
  float4 acc[16];
#pragma unroll
  for (int pp = 0; pp < 16; ++pp) acc[pp] = make_float4(0.f, 0.f, 0.f, 0.f);

#pragma unroll 2
  for (int k4 = 0; k4 < 64; ++k4) {
    float4 w0 = m4[(4 * k4 + 0) * 256 + t];
    float4 w1 = m4[(4 * k4 + 1) * 256 + t];
    float4 w2 = m4[(4 * k4 + 2) * 256 + t];
    float4 w3 = m4[(4 * k4 + 3) * 256 + t];
#pragma unroll
    for (int pp = 0; pp < 16; ++pp) {
      float4 zv = *(const float4*)&zs[pp * 256 + k4 * 4];
      fma4(acc[pp], zv.x, w0);
      fma4(acc[pp], zv.y, w1);
      fma4(acc[pp], zv.z, w2);
      fma4(acc[pp], zv.w, w3);
    }
  }
  float total = 0.f;
#pragma unroll
  for (int pp = 0; pp < 16; ++pp) {
    float r;
    r = fmaxf(acc[pp].x, 0.f); total = fmaf(r, r, total);
    r = fmaxf(acc[pp].y, 0.f); total = fmaf(r, r, total);
    r = fmaxf(acc[pp].z, 0.f); total = fmaf(r, r, total);
    r = fmaxf(acc[pp].w, 0.f); total = fmaf(r, r, total);
  }
  float r = block_sum_256(total, tmp);
  if (t == 0) atomicAdd(out + b, -r);
}

__global__ __launch_bounds__(256) void k_attn(const float* __restrict__ z,
                                              const float* __restrict__ wq,
                                              const float* __restrict__ wk,
                                              float* __restrict__ out) {
  __shared__ float lds[8192];
  __shared__ float red[4];
  const int b = blockIdx.x >> 1, half = blockIdx.x & 1;
  const int t = threadIdx.x;
  const int lane = t & 63;
  const int w = __builtin_amdgcn_readfirstlane(t >> 6);
  const float4* zb4 = (const float4*)(z + (size_t)b * 16384);

  float qa[4][8], ka[4][8];
#pragma unroll
  for (int hh = 0; hh < 4; ++hh)
#pragma unroll
    for (int j = 0; j < 8; ++j) { qa[hh][j] = 0.f; ka[hh][j] = 0.f; }

  float4* lds4 = (float4*)lds;
  for (int dc = 0; dc < 2; ++dc) {
    __syncthreads();
    for (int i = t; i < 2048; i += 256) {
      int p = i >> 5, ld4 = i & 31;
      lds4[ld4 * 64 + (p ^ (ld4 & 7))] = zb4[p * 64 + dc * 32 + ld4];
    }
    __syncthreads();
#pragma unroll
    for (int hh = 0; hh < 4; ++hh) {
      int h = half * 4 + hh;
      const float* Wqb = wq + (size_t)h * 8192 + (size_t)(w * 8) * 256 + dc * 128;
      const float* Wkb = wk + (size_t)h * 8192 + (size_t)(w * 8) * 256 + dc * 128;
      for (int ld4 = 0; ld4 < 32; ++ld4) {
        float4 wv[8], kv[8];
#pragma unroll
        for (int j = 0; j < 8; ++j) {
          wv[j] = *(const float4*)(Wqb + j * 256 + ld4 * 4);
          kv[j] = *(const float4*)(Wkb + j * 256 + ld4 * 4);
        }
        float4 zv = lds4[ld4 * 64 + (lane ^ (ld4 & 7))];
#pragma unroll
        for (int j = 0; j < 8; ++j) {
          qa[hh][j] = fmaf(wv[j].x, zv.x, fmaf(wv[j].y, zv.y,
                      fmaf(wv[j].z, zv.z, fmaf(wv[j].w, zv.w, qa[hh][j]))));
          ka[hh][j] = fmaf(kv[j].x, zv.x, fmaf(kv[j].y, zv.y,
                      fmaf(kv[j].z, zv.z, fmaf(kv[j].w, zv.w, ka[hh][j]))));
        }
      }
    }
  }

  float* Qs = lds;
  float* Ks = lds + 2048;
  float lse = 0.f;
#pragma unroll
  for (int hh = 0; hh < 4; ++hh) {
    __syncthreads();
#pragma unroll
    for (int j = 0; j < 8; ++j) {
      Qs[(w * 8 + j) * 64 + lane] = qa[hh][j];
      Ks[(w * 8 + j) * 64 + lane] = ka[hh][j];
    }
    __syncthreads();
    float av[16];
#pragma unroll
    for (int mm = 0; mm < 16; ++mm) av[mm] = 0.f;
    for (int rr = 0; rr < 32; ++rr) {
      float kv = Ks[rr * 64 + lane];
      const float* qrow = &Qs[rr * 64 + w * 16];
      float4 q0 = *(const float4*)(qrow + 0);
      float4 q1 = *(const float4*)(qrow + 4);
      float4 q2 = *(const float4*)(qrow + 8);
      float4 q3 = *(const float4*)(qrow + 12);
      av[0]  = fmaf(q0.x, kv, av[0]);  av[1]  = fmaf(q0.y, kv, av[1]);
      av[2]  = fmaf(q0.z, kv, av[2]);  av[3]  = fmaf(q0.w, kv, av[3]);
      av[4]  = fmaf(q1.x, kv, av[4]);  av[5]  = fmaf(q1.y, kv, av[5]);
      av[6]  = fmaf(q1.z, kv, av[6]);  av[7]  = fmaf(q1.w, kv, av[7]);
      av[8]  = fmaf(q2.x, kv, av[8]);  av[9]  = fmaf(q2.y, kv, av[9]);
      av[10] = fmaf(q2.z, kv, av[10]); av[11] = fmaf(q2.w, kv, av[11]);
      av[12] = fmaf(q3.x, kv, av[12]); av[13] = fmaf(q3.y, kv, av[13]);
      av[14] = fmaf(q3.z, kv, av[14]); av[15] = fmaf(q3.w, kv, av[15]);
    }
#pragma unroll
    for (int mm = 0; mm < 16; ++mm) {
      float e = __expf(GAMMA * av[mm]);
#pragma unroll
      for (int off = 32; off; off >>= 1) e += __shfl_xor(e, off, 64);
      lse += __logf(e);
    }
  }
  if (lane == 0) red[w] = lse;
  __syncthreads();
  if (t == 0)
    atomicAdd(out + b, -(red[0] + red[1] + red[2] + red[3]) * (1.0f / GAMMA));
}

// ---------------------------------------------------------------------------
extern "C" void kernel_launch(void* const* d_in, const int* in_sizes, int n_in,
                              void* d_out, int out_size, void* d_ws,
                              size_t ws_size, hipStream_t stream) {
  (void)in_sizes; (void)n_in; (void)out_size;
  const float* x  = (const float*)d_in[0];
  const float* z  = (const float*)d_in[1];
  const float* ew = (const float*)d_in[2];
  const float* eb = (const float*)d_in[3];
  const float* vb = (const float*)d_in[4];
  const float* pb = (const float*)d_in[5];
  const float* mw = (const float*)d_in[6];
  const float* wq = (const float*)d_in[7];
  const float* wk = (const float*)d_in[8];
  float* out = (float*)d_out;

  const size_t MT_B = (size_t)1024 * 256 * 2;   // 512 KB mtf
  const size_t WC_B = (size_t)512 * 256 * 2;    // 256 KB wcf
  const size_t EW_B = (size_t)96 * 64 * 8 * 2;  // 96 KB ewt
  const size_t FULL = MT_B + WC_B + EW_B;       // ~0.86 MB

  ushort* mtf = (ushort*)d_ws;
  ushort* wcf = (ushort*)((char*)d_ws + MT_B);
  ushort* ewt = (ushort*)((char*)d_ws + MT_B + WC_B);

  if (ws_size >= FULL) {
    k_cvt_weights_v4<<<216, 256, 0, stream>>>(wq, wk, ew, mw, wcf, ewt, mtf);
    k_mega2 <<<1024, 256, 0, stream>>>(z, eb, pb, mtf, wcf, out);
    k_enc_v5<<<1024, 256, 0, stream>>>(x, vb, z, ewt, out);
  } else {
    k_xz  <<<1024, 256, 0, stream>>>(x, z, vb, eb, pb, out);
    k_enc <<<1024, 256, 0, stream>>>(x, z, ew, out);
    k_mem <<<4096, 256, 0, stream>>>(z, mw, out);
    k_attn<<<2048, 256, 0, stream>>>(z, wq, wk, out);
  }
}

// Round 8
// 287.413 us; speedup vs baseline: 1.0467x; 1.0467x over previous
//
#include <hip/hip_runtime.h>
#include <hip/hip_bf16.h>

#define GAMMA 0.25f

// Shapes: B=1024, C=3, H=64, D=256, NP=64 (8x8 grid of 8x8 patches),
//         M=1024, NH=8, R=32, P=8.  fp32 in/out.  out[b] = quad - coupling.
//
// R8 (= R7 resubmitted; R7 bench was an infra failure, kernel unmeasured).
// Recover from R6's spill disaster (launch_bounds(256,3) -> VGPR 84,
// acc spilled: WRITE_SIZE 123MB of scratch).  k_mega3 = R5 structure with:
//  - NO launch-bounds occupancy floor (compiler free: ~130 VGPR, no spill);
//  - 48KB LDS (zf 32KB frag-ordered + dstg 16KB head-pair) -> 3 blocks/CU;
//  - phase 0 reads z fp32 in FRAGMENT order (16x128B segments/wave) and
//    writes zf linearly (lane i -> bytes 16i): conflict-free, no swizzle.
// k_enc_v6 = enc_v3's barrier-free depth-8 ewt prefetch + fp32 z A-frags.

typedef __attribute__((ext_vector_type(8))) short short8;  // 8 bf16 (4 VGPRs)
typedef __attribute__((ext_vector_type(4))) float f32x4;   // 4 fp32 acc

// dstg byte-addr XOR swizzle (bits 4-6; rows = 256B)
#define DG_SWZ(a) ((a) ^ ((((a) >> 8) & 7) << 4))

__device__ __forceinline__ float dot4(float4 a, float4 b) {
  return fmaf(a.x, b.x, fmaf(a.y, b.y, fmaf(a.z, b.z, a.w * b.w)));
}

__device__ __forceinline__ void fma4(float4& a, float s, float4 w) {
  a.x = fmaf(s, w.x, a.x); a.y = fmaf(s, w.y, a.y);
  a.z = fmaf(s, w.z, a.z); a.w = fmaf(s, w.w, a.w);
}

__device__ __forceinline__ ushort f2bf(float f) {
  __hip_bfloat16 h = __float2bfloat16(f);  // RNE
  return *reinterpret_cast<ushort*>(&h);
}

__device__ __forceinline__ float bf2f(ushort u) {
  union { unsigned int i; float f; } v;
  v.i = ((unsigned int)u) << 16;
  return v.f;
}

// 256-thread block sum; result valid on all threads.
__device__ __forceinline__ float block_sum_256(float v, float* tmp) {
#pragma unroll
  for (int off = 32; off; off >>= 1) v += __shfl_down(v, off, 64);
  int w = threadIdx.x >> 6;
  if ((threadIdx.x & 63) == 0) tmp[w] = v;
  __syncthreads();
  return tmp[0] + tmp[1] + tmp[2] + tmp[3];
}

// ---------------------------------------------------------------------------
// Weight conversion, fragment-linear (one launch, block ranges):
// [0,64)   wcf: frag=ctg*8+kc (ctg 0..31): Wcat cols [h][qk][rr], 256 frags
// [64,88)  ewt: frag=ks*12+ct: B[d][kcol]=ew[d*192+kcol]   96 frags
// [88,216) mtf: frag=C*8+kc:   B[k][m]=mw[k][C*16+m]      512 frags
// Each fragment = contiguous [l][8] 1KB wave-block.
// ---------------------------------------------------------------------------
__global__ __launch_bounds__(256) void k_cvt_weights_v4(
    const float* __restrict__ wq, const float* __restrict__ wk,
    const float* __restrict__ ew, const float* __restrict__ mw,
    ushort* __restrict__ wcf, ushort* __restrict__ ewt,
    ushort* __restrict__ mtf) {
  int bid = blockIdx.x, t = threadIdx.x;
  ushort o[8];
  if (bid < 64) {
    int tid = bid * 256 + t;  // 0..16383
    int frag = tid >> 6, l = tid & 63;
    int ctg = frag >> 3, kc = frag & 7;
    int col = ctg * 16 + (l & 15);
    int h = col >> 6, qk = (col >> 5) & 1, rr = col & 31;
    int k0 = kc * 32 + (l >> 4) * 8;
    const float* s = (qk ? wk : wq) + ((size_t)h * 32 + rr) * 256 + k0;
#pragma unroll
    for (int i = 0; i < 8; ++i) o[i] = f2bf(s[i]);
    *(ushort4*)(wcf + (size_t)tid * 8) = *(ushort4*)&o[0];
    *(ushort4*)(wcf + (size_t)tid * 8 + 4) = *(ushort4*)&o[4];
  } else if (bid < 88) {
    int tid = (bid - 64) * 256 + t;  // 0..6143
    int frag = tid >> 6, l = tid & 63;
    int ks = frag / 12, ct = frag % 12;
    const float* s = ew + (size_t)(ks * 32 + (l >> 4) * 8) * 192 +
                     ct * 16 + (l & 15);
#pragma unroll
    for (int i = 0; i < 8; ++i) o[i] = f2bf(s[(size_t)i * 192]);
    *(ushort4*)(ewt + (size_t)tid * 8) = *(ushort4*)&o[0];
    *(ushort4*)(ewt + (size_t)tid * 8 + 4) = *(ushort4*)&o[4];
  } else {
    int tid = (bid - 88) * 256 + t;  // 0..32767
    int frag = tid >> 6, l = tid & 63;
    int C = frag >> 3, kc = frag & 7;
    int k0 = kc * 32 + (l >> 4) * 8, col = C * 16 + (l & 15);
#pragma unroll
    for (int i = 0; i < 8; ++i) o[i] = f2bf(mw[(size_t)(k0 + i) * 1024 + col]);
    *(ushort4*)(mtf + (size_t)tid * 8) = *(ushort4*)&o[0];
    *(ushort4*)(mtf + (size_t)tid * 8 + 4) = *(ushort4*)&o[4];
  }
}

// ---------------------------------------------------------------------------
// Mega-kernel v3: quad_z - phi_bias - phi_pos - phi_mem - phi_att, per b.
// LDS 48KB: zf = frag-ordered z[b] bf16 (32KB, linear writes), dstg =
// swizzled [64][128] bf16 head-pair Q|K tile (16KB).  ~3 blocks/CU natural.
// ---------------------------------------------------------------------------
__global__ __launch_bounds__(256) void k_mega3(
    const float* __restrict__ z, const float* __restrict__ eb,
    const float* __restrict__ pb, const ushort* __restrict__ mtf,
    const ushort* __restrict__ wcf, float* __restrict__ out) {
  __shared__ char SL[49152];  // 48 KB
  __shared__ float tmp[4];
  ushort* zf = (ushort*)SL;   // 32 KB, frag-ordered [w2*8+ks][l][8]
  char* dgb = SL + 32768;     // 16 KB
  const int t = threadIdx.x, l = t & 63, w = t >> 6;
  const int b = blockIdx.x;
  const int q = l >> 4, m = l & 15;
  float s = 0.f;

  // ---- Phase 0: z fp32 fragment-gather -> quad terms + zf (linear writes).
  // Per j, per wave: fixed (w2,ks); lanes read 16 rows x 128B contiguous.
  {
    const float* zb = z + (size_t)b * 16384;
#pragma unroll
    for (int j = 0; j < 8; ++j) {
      int i = t + j * 256;
      int l2 = i & 63, ks = (i >> 6) & 7, w2 = i >> 9;
      int row = 16 * w2 + (l2 & 15);
      int k0 = ks * 32 + (l2 >> 4) * 8;
      const float* src = zb + (size_t)row * 256 + k0;
      float4 u = *(const float4*)(src);
      float4 v = *(const float4*)(src + 4);
      const float* pbp = pb + (size_t)row * 256 + k0;
      float4 pu = *(const float4*)(pbp);
      float4 pv = *(const float4*)(pbp + 4);
      float4 eu = *(const float4*)(eb + k0);
      float4 ev = *(const float4*)(eb + k0 + 4);
      float4 cu, cv;
      cu.x = pu.x + eu.x; cu.y = pu.y + eu.y;
      cu.z = pu.z + eu.z; cu.w = pu.w + eu.w;
      cv.x = pv.x + ev.x; cv.y = pv.y + ev.y;
      cv.z = pv.z + ev.z; cv.w = pv.w + ev.w;
      s += 0.5f * dot4(u, u) - dot4(u, cu);
      s += 0.5f * dot4(v, v) - dot4(v, cv);
      ushort o[8];
      o[0] = f2bf(u.x); o[1] = f2bf(u.y); o[2] = f2bf(u.z); o[3] = f2bf(u.w);
      o[4] = f2bf(v.x); o[5] = f2bf(v.y); o[6] = f2bf(v.z); o[7] = f2bf(v.w);
      *(short8*)(zf + (size_t)i * 8) = *(short8*)o;  // linear: no conflicts
    }
  }
  __syncthreads();

  // ---- Phase 1: phi_mem (4 ct chunks, barrier-free; B from L2 mtf).
#pragma unroll 1
  for (int ct = 0; ct < 4; ++ct) {
    const ushort* Bb = mtf + ((size_t)(ct * 16 + w * 4) * 8) * 512 +
                       (size_t)l * 8;
    short8 fb[2][4];
#pragma unroll
    for (int c = 0; c < 4; ++c) fb[0][c] = *(const short8*)(Bb + (c * 8 + 0) * 512);
#pragma unroll
    for (int c = 0; c < 4; ++c) fb[1][c] = *(const short8*)(Bb + (c * 8 + 1) * 512);

    f32x4 acc[4][4];
#pragma unroll
    for (int r = 0; r < 4; ++r)
#pragma unroll
      for (int c = 0; c < 4; ++c) acc[r][c] = f32x4{0.f, 0.f, 0.f, 0.f};

#pragma unroll
    for (int kc = 0; kc < 8; ++kc) {
      const int cur = kc & 1;
      short8 a4[4];
#pragma unroll
      for (int r = 0; r < 4; ++r)
        a4[r] = *(const short8*)(zf + (size_t)((r * 8 + kc) * 64 + l) * 8);
#pragma unroll
      for (int r = 0; r < 4; ++r)
#pragma unroll
        for (int c = 0; c < 4; ++c)
          acc[r][c] = __builtin_amdgcn_mfma_f32_16x16x32_bf16(a4[r], fb[cur][c],
                                                              acc[r][c], 0, 0, 0);
      if (kc < 6) {
#pragma unroll
        for (int c = 0; c < 4; ++c)
          fb[cur][c] = *(const short8*)(Bb + (c * 8 + kc + 2) * 512);
      }
    }
#pragma unroll
    for (int r = 0; r < 4; ++r)
#pragma unroll
      for (int c = 0; c < 4; ++c)
#pragma unroll
        for (int e = 0; e < 4; ++e) {
          float rr = fmaxf(acc[r][c][e], 0.f);
          s -= rr * rr;
        }
  }

  // ---- Phase 2: phi_att, 4 head-pair iterations (heads 2hp, 2hp+1).
  float part = 0.f;
#pragma unroll 1
  for (int hp = 0; hp < 4; ++hp) {
    // wave w owns col-tile group ctg = hp*8 + w*2 + c (c in 0..1).
    const ushort* Bb = wcf + ((size_t)((hp * 8 + w * 2) * 8)) * 512 +
                       (size_t)l * 8;
    short8 fb[2][2];
#pragma unroll
    for (int c = 0; c < 2; ++c) fb[0][c] = *(const short8*)(Bb + (c * 8 + 0) * 512);
#pragma unroll
    for (int c = 0; c < 2; ++c) fb[1][c] = *(const short8*)(Bb + (c * 8 + 1) * 512);

    f32x4 acc[4][2];
#pragma unroll
    for (int r = 0; r < 4; ++r)
#pragma unroll
      for (int c = 0; c < 2; ++c) acc[r][c] = f32x4{0.f, 0.f, 0.f, 0.f};

#pragma unroll
    for (int kc = 0; kc < 8; ++kc) {
      const int cur = kc & 1;
      short8 a4[4];
#pragma unroll
      for (int r = 0; r < 4; ++r)
        a4[r] = *(const short8*)(zf + (size_t)((r * 8 + kc) * 64 + l) * 8);
#pragma unroll
      for (int r = 0; r < 4; ++r)
#pragma unroll
        for (int c = 0; c < 2; ++c)
          acc[r][c] = __builtin_amdgcn_mfma_f32_16x16x32_bf16(a4[r], fb[cur][c],
                                                              acc[r][c], 0, 0, 0);
      if (kc < 6) {
#pragma unroll
        for (int c = 0; c < 2; ++c)
          fb[cur][c] = *(const short8*)(Bb + (c * 8 + kc + 2) * 512);
      }
    }

    // Store D (row = 16rt+4q+reg, local col lc = (2w+c)*16+m) -> dstg.
#pragma unroll
    for (int rt = 0; rt < 4; ++rt)
#pragma unroll
      for (int c = 0; c < 2; ++c)
#pragma unroll
        for (int reg = 0; reg < 4; ++reg) {
          int row = 16 * rt + 4 * q + reg;
          int lc = (2 * w + c) * 16 + m;
          int ba = row * 256 + lc * 2;
          *(ushort*)(dgb + DG_SWZ(ba)) = f2bf(acc[rt][c][reg]);
        }
    __syncthreads();

    // QK^T + lse for the two heads (Q cols hh*64.., K cols hh*64+32..).
#pragma unroll
    for (int hh = 0; hh < 2; ++hh) {
      int rowq = 16 * w + m;
      short8 qa = *(const short8*)(
          dgb + DG_SWZ(rowq * 256 + (hh * 64 + q * 8) * 2));
      f32x4 a2[4];
#pragma unroll
      for (int nt = 0; nt < 4; ++nt) {
        int rowk = 16 * nt + m;
        a2[nt] = __builtin_amdgcn_mfma_f32_16x16x32_bf16(
            qa,
            *(const short8*)(dgb + DG_SWZ(rowk * 256 + (hh * 64 + 32 + q * 8) * 2)),
            f32x4{0.f, 0.f, 0.f, 0.f}, 0, 0, 0);
      }
#pragma unroll
      for (int reg = 0; reg < 4; ++reg) {
        float e = __expf(GAMMA * a2[0][reg]) + __expf(GAMMA * a2[1][reg]) +
                  __expf(GAMMA * a2[2][reg]) + __expf(GAMMA * a2[3][reg]);
        e += __shfl_xor(e, 1, 64);
        e += __shfl_xor(e, 2, 64);
        e += __shfl_xor(e, 4, 64);
        e += __shfl_xor(e, 8, 64);
        part += (m == 0) ? __logf(e) : 0.f;  // one log per row 16w+4q+reg
      }
    }
    __syncthreads();  // dstg reads done before next pair's writes
  }
  s -= part * (1.0f / GAMMA);

  float r = block_sum_256(s, tmp);
  if (t == 0) out[b] = r;
}

// ---------------------------------------------------------------------------
// Kernel: quad_x - phi_vis - phi_enc.  enc_v3 structure: depth-8 rotating
// register prefetch of ewt from L2 (no LDS staging, no inner barriers);
// z A-frags gathered from fp32; epilogue dots D against x in LDS.
// ---------------------------------------------------------------------------
__global__ __launch_bounds__(256) void k_enc_v6(
    const float* __restrict__ x, const float* __restrict__ vb,
    const float* __restrict__ z, const ushort* __restrict__ ewt,
    float* __restrict__ out) {
  __shared__ ushort xs[12288];  // 24 KB: x[b] bf16, NCHW layout
  __shared__ float tmp[4];
  const int b = blockIdx.x, t = threadIdx.x, l = t & 63, w = t >> 6;
  const int q = l >> 4, m = l & 15;

  // z A-frags from fp32 (L3-warm after k_mega3); RNE cvt == bf16 path.
  const float* Zr = z + (size_t)b * 16384 + (size_t)(16 * w + m) * 256 + q * 8;
  short8 a[8];
#pragma unroll
  for (int ks = 0; ks < 8; ++ks) {
    float4 u = *(const float4*)(Zr + ks * 32);
    float4 v = *(const float4*)(Zr + ks * 32 + 4);
    ushort o[8];
    o[0] = f2bf(u.x); o[1] = f2bf(u.y); o[2] = f2bf(u.z); o[3] = f2bf(u.w);
    o[4] = f2bf(v.x); o[5] = f2bf(v.y); o[6] = f2bf(v.z); o[7] = f2bf(v.w);
    a[ks] = *(short8*)o;
  }

  // Stage x -> bf16 LDS; accumulate quad_x - phi_vis.
  const float4* xb = (const float4*)(x + (size_t)b * 12288);
  const float4* vb4 = (const float4*)vb;
  ushort4* xs4 = (ushort4*)xs;
  float s = 0.f;
  for (int i = t; i < 3072; i += 256) {
    float4 xv = xb[i];
    float4 bv = vb4[i];
    s += 0.5f * dot4(xv, xv) - dot4(bv, xv);
    ushort4 o;
    o.x = f2bf(xv.x); o.y = f2bf(xv.y); o.z = f2bf(xv.z); o.w = f2bf(xv.w);
    xs4[i] = o;
  }
  __syncthreads();

  f32x4 acc[12];
#pragma unroll
  for (int ct = 0; ct < 12; ++ct) acc[ct] = f32x4{0.f, 0.f, 0.f, 0.f};

  const ushort* Ep = ewt + (size_t)l * 8;
  short8 fb[8];
#pragma unroll
  for (int i = 0; i < 8; ++i) fb[i] = *(const short8*)(Ep + i * 512);
#pragma unroll
  for (int f = 0; f < 96; ++f) {
    const int ks = f / 12, ct = f % 12;
    acc[ct] = __builtin_amdgcn_mfma_f32_16x16x32_bf16(a[ks], fb[f & 7],
                                                      acc[ct], 0, 0, 0);
    if (f < 88) fb[f & 7] = *(const short8*)(Ep + (size_t)(f + 8) * 512);
  }

  // Epilogue: D element (row p=16w+4q+reg, col k=16ct+m) * x[p,k] from LDS.
#pragma unroll
  for (int ct = 0; ct < 12; ++ct) {
#pragma unroll
    for (int reg = 0; reg < 4; ++reg) {
      const int p = 16 * w + 4 * q + reg, gi = p >> 3, gj = p & 7;
      const int k = ct * 16 + m, c = k >> 6, r2 = k & 63;
      const int ii = r2 >> 3, jj = r2 & 7;
      s -= acc[ct][reg] * bf2f(xs[c * 4096 + (gi * 8 + ii) * 64 + gj * 8 + jj]);
    }
  }
  float r = block_sum_256(s, tmp);
  if (t == 0) atomicAdd(out + b, r);  // += quad_x - phi_vis - phi_enc
}

// ---------------------------------------------------------------------------
// Fallback kernels (no-workspace tier).
// ---------------------------------------------------------------------------
__global__ __launch_bounds__(256) void k_xz(const float* __restrict__ x,
                                            const float* __restrict__ z,
                                            const float* __restrict__ vb,
                                            const float* __restrict__ eb,
                                            const float* __restrict__ pb,
                                            float* __restrict__ out) {
  __shared__ float tmp[4];
  int b = blockIdx.x, t = threadIdx.x;
  const float4* xb = (const float4*)(x + (size_t)b * 12288);
  const float4* vb4 = (const float4*)vb;
  float s = 0.f;
  for (int i = t; i < 3072; i += 256) {
    float4 xv = xb[i];
    float4 bv = vb4[i];
    s += 0.5f * dot4(xv, xv) - dot4(bv, xv);
  }
  const float4* zb = (const float4*)(z + (size_t)b * 16384);
  const float4* pb4 = (const float4*)pb;
  const float4* eb4 = (const float4*)eb;
  for (int i = t; i < 4096; i += 256) {
    float4 zv = zb[i];
    float4 pv = pb4[i];
    float4 ev = eb4[i & 63];
    float4 c;
    c.x = pv.x + ev.x; c.y = pv.y + ev.y; c.z = pv.z + ev.z; c.w = pv.w + ev.w;
    s += 0.5f * dot4(zv, zv) - dot4(zv, c);
  }
  float r = block_sum_256(s, tmp);
  if (t == 0) out[b] = r;
}

__global__ __launch_bounds__(256) void k_enc(const float* __restrict__ x,
                                             const float* __restrict__ z,
                                             const float* __restrict__ ew,
                                             float* __restrict__ out) {
  __shared__ float xs[12288];
  __shared__ float tmp[4];
  int b = blockIdx.x, t = threadIdx.x;
  const float4* xb4 = (const float4*)(x + (size_t)b * 12288);
  for (int i = t; i < 3072; i += 256) ((float4*)xs)[i] = xb4[i];
  __syncthreads();

  float acc[64];
#pragma unroll
  for (int p = 0; p < 64; ++p) acc[p] = 0.f;

  for (int k4 = 0; k4 < 48; ++k4) {
    float4 wv = *(const float4*)(ew + (size_t)t * 192 + k4 * 4);
    int c = k4 >> 4;
    int ii = (k4 >> 1) & 7;
    int jh = (k4 & 1) * 4;
    const float* base = xs + c * 4096 + ii * 64 + jh;
#pragma unroll
    for (int p = 0; p < 64; ++p) {
      float4 pv = *(const float4*)(base + (p >> 3) * 512 + (p & 7) * 8);
      acc[p] = fmaf(wv.x, pv.x,
               fmaf(wv.y, pv.y, fmaf(wv.z, pv.z, fmaf(wv.w, pv.w, acc[p]))));
    }
  }
  const float* zb = z + (size_t)b * 16384;
  float s = 0.f;
#pragma unroll
  for (int p = 0; p < 64; ++p) s += acc[p] * zb[p * 256 + t];
  float r = block_sum_256(s, tmp);
  if (t == 0) atomicAdd(out + b, -r);
}

__global__ __launch_bounds__(256) void k_mem(const float* __restrict__ z,
                                             const float* __restrict__ mw,
                                             float* __restrict__ out) {
  __shared__ float zs[16 * 256];
  __shared__ float tmp[4];
  int b = blockIdx.x >> 2, pt = blockIdx.x & 3, t = threadIdx.x;
  const float4* zb4 = (const float4*)(z + (size_t)b * 16384 + pt * 4096);
  for (int i = t; i < 1024; i += 256) ((float4*)zs)[i] = zb4[i];
  __syncthreads();

  const float4* m4 = (const float4*)mw;
  float4 acc[16];
#pragma unroll
  for (int pp = 0; pp < 16; ++pp) acc[pp] = make_float4(0.f, 0.f, 0.f, 0.f);

#pragma unroll 2
  for (int k4 = 0; k4 < 64; ++k4) {
    float4 w0 = m4[(4 * k4 + 0) * 256 + t];
    float4 w1 = m4[(4 * k4 + 1) * 256 + t];
    float4 w2 = m4[(4 * k4 + 2) * 256 + t];
    float4 w3 = m4[(4 * k4 + 3) * 256 + t];
#pragma unroll
    for (int pp = 0; pp < 16; ++pp) {
      float4 zv = *(const float4*)&zs[pp * 256 + k4 * 4];
      fma4(acc[pp], zv.x, w0);
      fma4(acc[pp], zv.y, w1);
      fma4(acc[pp], zv.z, w2);
      fma4(acc[pp], zv.w, w3);
    }
  }
  float total = 0.f;
#pragma unroll
  for (int pp = 0; pp < 16; ++pp) {
    float r;
    r = fmaxf(acc[pp].x, 0.f); total = fmaf(r, r, total);
    r = fmaxf(acc[pp].y, 0.f); total = fmaf(r, r, total);
    r = fmaxf(acc[pp].z, 0.f); total = fmaf(r, r, total);
    r = fmaxf(acc[pp].w, 0.f); total = fmaf(r, r, total);
  }
  float r = block_sum_256(total, tmp);
  if (t == 0) atomicAdd(out + b, -r);
}

__global__ __launch_bounds__(256) void k_attn(const float* __restrict__ z,
                                              const float* __restrict__ wq,
                                              const float* __restrict__ wk,
                                              float* __restrict__ out) {
  __shared__ float lds[8192];
  __shared__ float red[4];
  const int b = blockIdx.x >> 1, half = blockIdx.x & 1;
  const int t = threadIdx.x;
  const int lane = t & 63;
  const int w = __builtin_amdgcn_readfirstlane(t >> 6);
  const float4* zb4 = (const float4*)(z + (size_t)b * 16384);

  float qa[4][8], ka[4][8];
#pragma unroll
  for (int hh = 0; hh < 4; ++hh)
#pragma unroll
    for (int j = 0; j < 8; ++j) { qa[hh][j] = 0.f; ka[hh][j] = 0.f; }

  float4* lds4 = (float4*)lds;
  for (int dc = 0; dc < 2; ++dc) {
    __syncthreads();
    for (int i = t; i < 2048; i += 256) {
      int p = i >> 5, ld4 = i & 31;
      lds4[ld4 * 64 + (p ^ (ld4 & 7))] = zb4[p * 64 + dc * 32 + ld4];
    }
    __syncthreads();
#pragma unroll
    for (int hh = 0; hh < 4; ++hh) {
      int h = half * 4 + hh;
      const float* Wqb = wq + (size_t)h * 8192 + (size_t)(w * 8) * 256 + dc * 128;
      const float* Wkb = wk + (size_t)h * 8192 + (size_t)(w * 8) * 256 + dc * 128;
      for (int ld4 = 0; ld4 < 32; ++ld4) {
        float4 wv[8], kv[8];
#pragma unroll
        for (int j = 0; j < 8; ++j) {
          wv[j] = *(const float4*)(Wqb + j * 256 + ld4 * 4);
          kv[j] = *(const float4*)(Wkb + j * 256 + ld4 * 4);
        }
        float4 zv = lds4[ld4 * 64 + (lane ^ (ld4 & 7))];
#pragma unroll
        for (int j = 0; j < 8; ++j) {
          qa[hh][j] = fmaf(wv[j].x, zv.x, fmaf(wv[j].y, zv.y,
                      fmaf(wv[j].z, zv.z, fmaf(wv[j].w, zv.w, qa[hh][j]))));
          ka[hh][j] = fmaf(kv[j].x, zv.x, fmaf(kv[j].y, zv.y,
                      fmaf(kv[j].z, zv.z, fmaf(kv[j].w, zv.w, ka[hh][j]))));
        }
      }
    }
  }

  float* Qs = lds;
  float* Ks = lds + 2048;
  float lse = 0.f;
#pragma unroll
  for (int hh = 0; hh < 4; ++hh) {
    __syncthreads();
#pragma unroll
    for (int j = 0; j < 8; ++j) {
      Qs[(w * 8 + j) * 64 + lane] = qa[hh][j];
      Ks[(w * 8 + j) * 64 + lane] = ka[hh][j];
    }
    __syncthreads();
    float av[16];
#pragma unroll
    for (int mm = 0; mm < 16; ++mm) av[mm] = 0.f;
    for (int rr = 0; rr < 32; ++rr) {
      float kv = Ks[rr * 64 + lane];
      const float* qrow = &Qs[rr * 64 + w * 16];
      float4 q0 = *(const float4*)(qrow + 0);
      float4 q1 = *(const float4*)(qrow + 4);
      float4 q2 = *(const float4*)(qrow + 8);
      float4 q3 = *(const float4*)(qrow + 12);
      av[0]  = fmaf(q0.x, kv, av[0]);  av[1]  = fmaf(q0.y, kv, av[1]);
      av[2]  = fmaf(q0.z, kv, av[2]);  av[3]  = fmaf(q0.w, kv, av[3]);
      av[4]  = fmaf(q1.x, kv, av[4]);  av[5]  = fmaf(q1.y, kv, av[5]);
      av[6]  = fmaf(q1.z, kv, av[6]);  av[7]  = fmaf(q1.w, kv, av[7]);
      av[8]  = fmaf(q2.x, kv, av[8]);  av[9]  = fmaf(q2.y, kv, av[9]);
      av[10] = fmaf(q2.z, kv, av[10]); av[11] = fmaf(q2.w, kv, av[11]);
      av[12] = fmaf(q3.x, kv, av[12]); av[13] = fmaf(q3.y, kv, av[13]);
      av[14] = fmaf(q3.z, kv, av[14]); av[15] = fmaf(q3.w, kv, av[15]);
    }
#pragma unroll
    for (int mm = 0; mm < 16; ++mm) {
      float e = __expf(GAMMA * av[mm]);
#pragma unroll
      for (int off = 32; off; off >>= 1) e += __shfl_xor(e, off, 64);
      lse += __logf(e);
    }
  }
  if (lane == 0) red[w] = lse;
  __syncthreads();
  if (t == 0)
    atomicAdd(out + b, -(red[0] + red[1] + red[2] + red[3]) * (1.0f / GAMMA));
}

// ---------------------------------------------------------------------------
extern "C" void kernel_launch(void* const* d_in, const int* in_sizes, int n_in,
                              void* d_out, int out_size, void* d_ws,
                              size_t ws_size, hipStream_t stream) {
  (void)in_sizes; (void)n_in; (void)out_size;
  const float* x  = (const float*)d_in[0];
  const float* z  = (const float*)d_in[1];
  const float* ew = (const float*)d_in[2];
  const float* eb = (const float*)d_in[3];
  const float* vb = (const float*)d_in[4];
  const float* pb = (const float*)d_in[5];
  const float* mw = (const float*)d_in[6];
  const float* wq = (const float*)d_in[7];
  const float* wk = (const float*)d_in[8];
  float* out = (float*)d_out;

  const size_t MT_B = (size_t)1024 * 256 * 2;   // 512 KB mtf
  const size_t WC_B = (size_t)512 * 256 * 2;    // 256 KB wcf
  const size_t EW_B = (size_t)96 * 64 * 8 * 2;  // 96 KB ewt
  const size_t FULL = MT_B + WC_B + EW_B;       // ~0.86 MB

  ushort* mtf = (ushort*)d_ws;
  ushort* wcf = (ushort*)((char*)d_ws + MT_B);
  ushort* ewt = (ushort*)((char*)d_ws + MT_B + WC_B);

  if (ws_size >= FULL) {
    k_cvt_weights_v4<<<216, 256, 0, stream>>>(wq, wk, ew, mw, wcf, ewt, mtf);
    k_mega3 <<<1024, 256, 0, stream>>>(z, eb, pb, mtf, wcf, out);
    k_enc_v6<<<1024, 256, 0, stream>>>(x, vb, z, ewt, out);
  } else {
    k_xz  <<<1024, 256, 0, stream>>>(x, z, vb, eb, pb, out);
    k_enc <<<1024, 256, 0, stream>>>(x, z, ew, out);
    k_mem <<<4096, 256, 0, stream>>>(z, mw, out);
    k_attn<<<2048, 256, 0, stream>>>(z, wq, wk, out);
  }
}

// Round 9
// 261.295 us; speedup vs baseline: 1.1513x; 1.1000x over previous
//
#include <hip/hip_runtime.h>
#include <hip/hip_bf16.h>

#define GAMMA 0.25f

// Shapes: B=1024, C=3, H=64, D=256, NP=64 (8x8 grid of 8x8 patches),
//         M=1024, NH=8, R=32, P=8.  fp32 in/out.  out[b] = quad - coupling.
//
// R9: single fused kernel k_omega = R5's measured-good k_mega (78us;
// phases 0-2 VERBATIM) + phase 3 = enc.  Key: enc's A-fragments ARE the
// zf fragment layout already in LDS (zf[w*8+ks][l] == z rows 16w+m), so
// enc's scattered fp32 z-gather disappears; after loading a[] to regs the
// 64KB SL is reused (ebuf dbuf 24KB over zf, xs 24KB over dead dstg).
// One launch for all per-b work, no atomics, single out[b] store.
// R8 post-mortem: mega3's restructure kept per-wave work identical
// (MfmaUtil*dur == R5's) but halved residency -- reverted to R5 bodies.

typedef __attribute__((ext_vector_type(8))) short short8;  // 8 bf16 (4 VGPRs)
typedef __attribute__((ext_vector_type(4))) float f32x4;   // 4 fp32 acc

__device__ __forceinline__ float dot4(float4 a, float4 b) {
  return fmaf(a.x, b.x, fmaf(a.y, b.y, fmaf(a.z, b.z, a.w * b.w)));
}

__device__ __forceinline__ void fma4(float4& a, float s, float4 w) {
  a.x = fmaf(s, w.x, a.x); a.y = fmaf(s, w.y, a.y);
  a.z = fmaf(s, w.z, a.z); a.w = fmaf(s, w.w, a.w);
}

__device__ __forceinline__ ushort f2bf(float f) {
  __hip_bfloat16 h = __float2bfloat16(f);  // RNE
  return *reinterpret_cast<ushort*>(&h);
}

__device__ __forceinline__ float bf2f(ushort u) {
  union { unsigned int i; float f; } v;
  v.i = ((unsigned int)u) << 16;
  return v.f;
}

// 256-thread block sum; result valid on all threads.
__device__ __forceinline__ float block_sum_256(float v, float* tmp) {
#pragma unroll
  for (int off = 32; off; off >>= 1) v += __shfl_down(v, off, 64);
  int w = threadIdx.x >> 6;
  if ((threadIdx.x & 63) == 0) tmp[w] = v;
  __syncthreads();
  return tmp[0] + tmp[1] + tmp[2] + tmp[3];
}

// ---------------------------------------------------------------------------
// Weight conversion, fragment-linear (one launch, block ranges):
// [0,64)   wcf: frag=ctg*8+kc (ctg 0..31): Wcat cols [h][qk][rr], 256 frags
// [64,88)  ewt: frag=ks*12+ct: B[d][kcol]=ew[d*192+kcol]   96 frags
// [88,216) mtf: frag=C*8+kc:   B[k][m]=mw[k][C*16+m]      512 frags
// Each fragment = contiguous [l][8] 1KB wave-block.
// ---------------------------------------------------------------------------
__global__ __launch_bounds__(256) void k_cvt_weights_v4(
    const float* __restrict__ wq, const float* __restrict__ wk,
    const float* __restrict__ ew, const float* __restrict__ mw,
    ushort* __restrict__ wcf, ushort* __restrict__ ewt,
    ushort* __restrict__ mtf) {
  int bid = blockIdx.x, t = threadIdx.x;
  ushort o[8];
  if (bid < 64) {
    int tid = bid * 256 + t;  // 0..16383
    int frag = tid >> 6, l = tid & 63;
    int ctg = frag >> 3, kc = frag & 7;
    int col = ctg * 16 + (l & 15);
    int h = col >> 6, qk = (col >> 5) & 1, rr = col & 31;
    int k0 = kc * 32 + (l >> 4) * 8;
    const float* s = (qk ? wk : wq) + ((size_t)h * 32 + rr) * 256 + k0;
#pragma unroll
    for (int i = 0; i < 8; ++i) o[i] = f2bf(s[i]);
    *(ushort4*)(wcf + (size_t)tid * 8) = *(ushort4*)&o[0];
    *(ushort4*)(wcf + (size_t)tid * 8 + 4) = *(ushort4*)&o[4];
  } else if (bid < 88) {
    int tid = (bid - 64) * 256 + t;  // 0..6143
    int frag = tid >> 6, l = tid & 63;
    int ks = frag / 12, ct = frag % 12;
    const float* s = ew + (size_t)(ks * 32 + (l >> 4) * 8) * 192 +
                     ct * 16 + (l & 15);
#pragma unroll
    for (int i = 0; i < 8; ++i) o[i] = f2bf(s[(size_t)i * 192]);
    *(ushort4*)(ewt + (size_t)tid * 8) = *(ushort4*)&o[0];
    *(ushort4*)(ewt + (size_t)tid * 8 + 4) = *(ushort4*)&o[4];
  } else {
    int tid = (bid - 88) * 256 + t;  // 0..32767
    int frag = tid >> 6, l = tid & 63;
    int C = frag >> 3, kc = frag & 7;
    int k0 = kc * 32 + (l >> 4) * 8, col = C * 16 + (l & 15);
#pragma unroll
    for (int i = 0; i < 8; ++i) o[i] = f2bf(mw[(size_t)(k0 + i) * 1024 + col]);
    *(ushort4*)(mtf + (size_t)tid * 8) = *(ushort4*)&o[0];
    *(ushort4*)(mtf + (size_t)tid * 8 + 4) = *(ushort4*)&o[4];
  }
}

// ---------------------------------------------------------------------------
// Omega kernel: the ENTIRE energy for one b.
// LDS 64KB: [0,32KB) zf (frag-ordered z bf16) -> later ebuf dbuf (24KB);
//           [32KB,64KB) dstg (attn Q|K tile)  -> later xs (24KB).
// ---------------------------------------------------------------------------
__global__ __launch_bounds__(256) void k_omega(
    const float* __restrict__ x, const float* __restrict__ z,
    const float* __restrict__ eb, const float* __restrict__ vb,
    const float* __restrict__ pb, const ushort* __restrict__ ewt,
    const ushort* __restrict__ mtf, const ushort* __restrict__ wcf,
    float* __restrict__ out) {
  __shared__ ushort SL[32768];  // 64 KB
  const int t = threadIdx.x, l = t & 63, w = t >> 6;
  const int b = blockIdx.x;
  const int q = l >> 4, m = l & 15;
  float s = 0.f;

  // ---- Phase 0 (R5 verbatim): z fp32 coalesced -> quad_z - phi_bias -
  // phi_pos; zf (bf16, frag-ordered) to LDS.
  {
    const float4* zb4 = (const float4*)(z + (size_t)b * 16384);
    const float4* pb4 = (const float4*)pb;
    const float4* eb4 = (const float4*)eb;
#pragma unroll
    for (int n = 0; n < 16; ++n) {
      int i = t + n * 256;
      float4 zv = zb4[i];
      float4 pv = pb4[i];
      float4 ev = eb4[i & 63];
      float4 c;
      c.x = pv.x + ev.x; c.y = pv.y + ev.y;
      c.z = pv.z + ev.z; c.w = pv.w + ev.w;
      s += 0.5f * dot4(zv, zv) - dot4(zv, c);
      int p = i >> 6, d4 = i & 63;
      int ks = d4 >> 3, sub = (d4 & 7) >> 1, e0 = (d4 & 1) * 4;
      int li = (p & 15) + sub * 16;
      ushort4 o;
      o.x = f2bf(zv.x); o.y = f2bf(zv.y); o.z = f2bf(zv.z); o.w = f2bf(zv.w);
      *(ushort4*)(SL + (size_t)(((p >> 4) * 8 + ks) * 64 + li) * 8 + e0) = o;
    }
  }
  __syncthreads();

  // ---- Phase 1 (R5 verbatim): phi_mem (4 ct chunks; B from L2 mtf).
#pragma unroll 1
  for (int ct = 0; ct < 4; ++ct) {
    const ushort* Bb = mtf + ((size_t)(ct * 16 + w * 4) * 8) * 512 +
                       (size_t)l * 8;
    short8 fb[2][4];
#pragma unroll
    for (int c = 0; c < 4; ++c) fb[0][c] = *(const short8*)(Bb + (c * 8 + 0) * 512);
#pragma unroll
    for (int c = 0; c < 4; ++c) fb[1][c] = *(const short8*)(Bb + (c * 8 + 1) * 512);

    f32x4 acc[4][4];
#pragma unroll
    for (int r = 0; r < 4; ++r)
#pragma unroll
      for (int c = 0; c < 4; ++c) acc[r][c] = f32x4{0.f, 0.f, 0.f, 0.f};

#pragma unroll
    for (int kc = 0; kc < 8; ++kc) {
      const int cur = kc & 1;
      short8 a4[4];
#pragma unroll
      for (int r = 0; r < 4; ++r)
        a4[r] = *(const short8*)(SL + (size_t)((r * 8 + kc) * 64 + l) * 8);
#pragma unroll
      for (int r = 0; r < 4; ++r)
#pragma unroll
        for (int c = 0; c < 4; ++c)
          acc[r][c] = __builtin_amdgcn_mfma_f32_16x16x32_bf16(a4[r], fb[cur][c],
                                                              acc[r][c], 0, 0, 0);
      if (kc < 6) {
#pragma unroll
        for (int c = 0; c < 4; ++c)
          fb[cur][c] = *(const short8*)(Bb + (c * 8 + kc + 2) * 512);
      }
    }
#pragma unroll
    for (int r = 0; r < 4; ++r)
#pragma unroll
      for (int c = 0; c < 4; ++c)
#pragma unroll
        for (int e = 0; e < 4; ++e) {
          float rr = fmaxf(acc[r][c][e], 0.f);
          s -= rr * rr;
        }
  }

  // ---- Phase 2 (R5 verbatim): phi_att (2 halves; dstg swizzled).
  float part = 0.f;
  char* dstg = (char*)(SL + 16384);
#pragma unroll 1
  for (int half = 0; half < 2; ++half) {
    const ushort* Bb = wcf + ((size_t)((half * 16 + w * 4) * 8)) * 512 +
                       (size_t)l * 8;
    short8 fb[2][4];
#pragma unroll
    for (int c = 0; c < 4; ++c) fb[0][c] = *(const short8*)(Bb + (c * 8 + 0) * 512);
#pragma unroll
    for (int c = 0; c < 4; ++c) fb[1][c] = *(const short8*)(Bb + (c * 8 + 1) * 512);

    f32x4 acc[4][4];
#pragma unroll
    for (int r = 0; r < 4; ++r)
#pragma unroll
      for (int c = 0; c < 4; ++c) acc[r][c] = f32x4{0.f, 0.f, 0.f, 0.f};

#pragma unroll
    for (int kc = 0; kc < 8; ++kc) {
      const int cur = kc & 1;
      short8 a4[4];
#pragma unroll
      for (int r = 0; r < 4; ++r)
        a4[r] = *(const short8*)(SL + (size_t)((r * 8 + kc) * 64 + l) * 8);
#pragma unroll
      for (int r = 0; r < 4; ++r)
#pragma unroll
        for (int c = 0; c < 4; ++c)
          acc[r][c] = __builtin_amdgcn_mfma_f32_16x16x32_bf16(a4[r], fb[cur][c],
                                                              acc[r][c], 0, 0, 0);
      if (kc < 6) {
#pragma unroll
        for (int c = 0; c < 4; ++c)
          fb[cur][c] = *(const short8*)(Bb + (c * 8 + kc + 2) * 512);
      }
    }

    // D (row = 16rt+4q+reg, col = (4w+c)*16+m) -> bf16 -> dstg, XOR-swizzled.
#pragma unroll
    for (int rt = 0; rt < 4; ++rt)
#pragma unroll
      for (int c = 0; c < 4; ++c)
#pragma unroll
        for (int reg = 0; reg < 4; ++reg) {
          int row = 16 * rt + 4 * q + reg;
          int col = (4 * w + c) * 16 + m;
          int ba = ((row * 256 + col) * 2) ^ ((row & 7) << 4);
          *(ushort*)(dstg + ba) = f2bf(acc[rt][c][reg]);
        }
    __syncthreads();

    // Phase C: per head hh, Q rows 16w+m, K tiles nt; cols hh*64 (+32 for K).
#pragma unroll
    for (int hh = 0; hh < 4; ++hh) {
      int rowq = 16 * w + m;
      short8 qa = *(const short8*)(
          dstg + (((rowq * 256 + hh * 64 + q * 8) * 2) ^ ((rowq & 7) << 4)));
      f32x4 a2[4];
#pragma unroll
      for (int nt = 0; nt < 4; ++nt) {
        int rowk = 16 * nt + m;
        short8 kb = *(const short8*)(
            dstg + (((rowk * 256 + hh * 64 + 32 + q * 8) * 2) ^ ((rowk & 7) << 4)));
        a2[nt] = __builtin_amdgcn_mfma_f32_16x16x32_bf16(
            qa, kb, f32x4{0.f, 0.f, 0.f, 0.f}, 0, 0, 0);
      }
#pragma unroll
      for (int reg = 0; reg < 4; ++reg) {
        float e = __expf(GAMMA * a2[0][reg]) + __expf(GAMMA * a2[1][reg]) +
                  __expf(GAMMA * a2[2][reg]) + __expf(GAMMA * a2[3][reg]);
        e += __shfl_xor(e, 1, 64);
        e += __shfl_xor(e, 2, 64);
        e += __shfl_xor(e, 4, 64);
        e += __shfl_xor(e, 8, 64);
        part += (m == 0) ? __logf(e) : 0.f;  // one log per row 16w+4q+reg
      }
    }
    __syncthreads();  // dstg reads done before next half's writes
  }
  s -= part * (1.0f / GAMMA);

  // ---- Phase 3: quad_x - phi_vis - phi_enc.
  // A-frags straight from zf in LDS (same layout as phase-1's A-reads,
  // rows 16w+m).  Then SL is reused: ebuf dbuf at [0,24KB), xs at [32,56KB).
  short8 ae[8];
#pragma unroll
  for (int ks = 0; ks < 8; ++ks)
    ae[ks] = *(const short8*)(SL + (size_t)((w * 8 + ks) * 64 + l) * 8);
  short8 st[3];
#pragma unroll
  for (int i2 = 0; i2 < 3; ++i2)
    st[i2] = *(const short8*)(ewt + (size_t)(t + i2 * 256) * 8);
  __syncthreads();  // all zf reads complete; SL reusable

  ushort* ebuf0 = SL;          // 12 KB
  ushort* ebuf1 = SL + 6144;   // 12 KB
  ushort* xs    = SL + 16384;  // 24 KB (old dstg region)

  const float4* xb = (const float4*)(x + (size_t)b * 12288);
  const float4* vb4 = (const float4*)vb;
  ushort4* xs4 = (ushort4*)xs;
  for (int i2 = t; i2 < 3072; i2 += 256) {
    float4 xv = xb[i2];
    float4 bv = vb4[i2];
    s += 0.5f * dot4(xv, xv) - dot4(bv, xv);
    ushort4 o;
    o.x = f2bf(xv.x); o.y = f2bf(xv.y); o.z = f2bf(xv.z); o.w = f2bf(xv.w);
    xs4[i2] = o;
  }
#pragma unroll
  for (int i2 = 0; i2 < 3; ++i2)
    *(short8*)(ebuf0 + (size_t)(t + i2 * 256) * 8) = st[i2];
  __syncthreads();

  f32x4 acc[12];
#pragma unroll
  for (int ct = 0; ct < 12; ++ct) acc[ct] = f32x4{0.f, 0.f, 0.f, 0.f};

#pragma unroll
  for (int ks = 0; ks < 8; ++ks) {
    ushort* eb_cur = (ks & 1) ? ebuf1 : ebuf0;
    ushort* eb_nxt = (ks & 1) ? ebuf0 : ebuf1;
    if (ks < 7) {
#pragma unroll
      for (int i2 = 0; i2 < 3; ++i2)
        st[i2] = *(const short8*)(ewt + (size_t)(ks + 1) * 6144 +
                                  (size_t)(t + i2 * 256) * 8);
    }
#pragma unroll
    for (int ct = 0; ct < 12; ++ct) {
      short8 bv = *(const short8*)(eb_cur + (size_t)(ct * 64 + l) * 8);
      acc[ct] = __builtin_amdgcn_mfma_f32_16x16x32_bf16(ae[ks], bv, acc[ct], 0, 0, 0);
    }
    if (ks < 7) {
#pragma unroll
      for (int i2 = 0; i2 < 3; ++i2)
        *(short8*)(eb_nxt + (size_t)(t + i2 * 256) * 8) = st[i2];
    }
    __syncthreads();
  }

  // Epilogue: D element (row p=16w+4q+reg, col k=16ct+m) * x[p,k] from LDS.
#pragma unroll
  for (int ct = 0; ct < 12; ++ct) {
#pragma unroll
    for (int reg = 0; reg < 4; ++reg) {
      const int p = 16 * w + 4 * q + reg, gi = p >> 3, gj = p & 7;
      const int k = ct * 16 + m, c = k >> 6, r2 = k & 63;
      const int ii = r2 >> 3, jj = r2 & 7;
      s -= acc[ct][reg] * bf2f(xs[c * 4096 + (gi * 8 + ii) * 64 + gj * 8 + jj]);
    }
  }

  float r = block_sum_256(s, (float*)SL);  // ebuf dead; disjoint from xs
  if (t == 0) out[b] = r;
}

// ---------------------------------------------------------------------------
// Fallback kernels (no-workspace tier).
// ---------------------------------------------------------------------------
__global__ __launch_bounds__(256) void k_xz(const float* __restrict__ x,
                                            const float* __restrict__ z,
                                            const float* __restrict__ vb,
                                            const float* __restrict__ eb,
                                            const float* __restrict__ pb,
                                            float* __restrict__ out) {
  __shared__ float tmp[4];
  int b = blockIdx.x, t = threadIdx.x;
  const float4* xb = (const float4*)(x + (size_t)b * 12288);
  const float4* vb4 = (const float4*)vb;
  float s = 0.f;
  for (int i = t; i < 3072; i += 256) {
    float4 xv = xb[i];
    float4 bv = vb4[i];
    s += 0.5f * dot4(xv, xv) - dot4(bv, xv);
  }
  const float4* zb = (const float4*)(z + (size_t)b * 16384);
  const float4* pb4 = (const float4*)pb;
  const float4* eb4 = (const float4*)eb;
  for (int i = t; i < 4096; i += 256) {
    float4 zv = zb[i];
    float4 pv = pb4[i];
    float4 ev = eb4[i & 63];
    float4 c;
    c.x = pv.x + ev.x; c.y = pv.y + ev.y; c.z = pv.z + ev.z; c.w = pv.w + ev.w;
    s += 0.5f * dot4(zv, zv) - dot4(zv, c);
  }
  float r = block_sum_256(s, tmp);
  if (t == 0) out[b] = r;
}

__global__ __launch_bounds__(256) void k_enc(const float* __restrict__ x,
                                             const float* __restrict__ z,
                                             const float* __restrict__ ew,
                                             float* __restrict__ out) {
  __shared__ float xs[12288];
  __shared__ float tmp[4];
  int b = blockIdx.x, t = threadIdx.x;
  const float4* xb4 = (const float4*)(x + (size_t)b * 12288);
  for (int i = t; i < 3072; i += 256) ((float4*)xs)[i] = xb4[i];
  __syncthreads();

  float acc[64];
#pragma unroll
  for (int p = 0; p < 64; ++p) acc[p] = 0.f;

  for (int k4 = 0; k4 < 48; ++k4) {
    float4 wv = *(const float4*)(ew + (size_t)t * 192 + k4 * 4);
    int c = k4 >> 4;
    int ii = (k4 >> 1) & 7;
    int jh = (k4 & 1) * 4;
    const float* base = xs + c * 4096 + ii * 64 + jh;
#pragma unroll
    for (int p = 0; p < 64; ++p) {
      float4 pv = *(const float4*)(base + (p >> 3) * 512 + (p & 7) * 8);
      acc[p] = fmaf(wv.x, pv.x,
               fmaf(wv.y, pv.y, fmaf(wv.z, pv.z, fmaf(wv.w, pv.w, acc[p]))));
    }
  }
  const float* zb = z + (size_t)b * 16384;
  float s = 0.f;
#pragma unroll
  for (int p = 0; p < 64; ++p) s += acc[p] * zb[p * 256 + t];
  float r = block_sum_256(s, tmp);
  if (t == 0) atomicAdd(out + b, -r);
}

__global__ __launch_bounds__(256) void k_mem(const float* __restrict__ z,
                                             const float* __restrict__ mw,
                                             float* __restrict__ out) {
  __shared__ float zs[16 * 256];
  __shared__ float tmp[4];
  int b = blockIdx.x >> 2, pt = blockIdx.x & 3, t = threadIdx.x;
  const float4* zb4 = (const float4*)(z + (size_t)b * 16384 + pt * 4096);
  for (int i = t; i < 1024; i += 256) ((float4*)zs)[i] = zb4[i];
  __syncthreads();

  const float4* m4 = (const float4*)mw;
  float4 acc[16];
#pragma unroll
  for (int pp = 0; pp < 16; ++pp) acc[pp] = make_float4(0.f, 0.f, 0.f, 0.f);

#pragma unroll 2
  for (int k4 = 0; k4 < 64; ++k4) {
    float4 w0 = m4[(4 * k4 + 0) * 256 + t];
    float4 w1 = m4[(4 * k4 + 1) * 256 + t];
    float4 w2 = m4[(4 * k4 + 2) * 256 + t];
    float4 w3 = m4[(4 * k4 + 3) * 256 + t];
#pragma unroll
    for (int pp = 0; pp < 16; ++pp) {
      float4 zv = *(const float4*)&zs[pp * 256 + k4 * 4];
      fma4(acc[pp], zv.x, w0);
      fma4(acc[pp], zv.y, w1);
      fma4(acc[pp], zv.z, w2);
      fma4(acc[pp], zv.w, w3);
    }
  }
  float total = 0.f;
#pragma unroll
  for (int pp = 0; pp < 16; ++pp) {
    float r;
    r = fmaxf(acc[pp].x, 0.f); total = fmaf(r, r, total);
    r = fmaxf(acc[pp].y, 0.f); total = fmaf(r, r, total);
    r = fmaxf(acc[pp].z, 0.f); total = fmaf(r, r, total);
    r = fmaxf(acc[pp].w, 0.f); total = fmaf(r, r, total);
  }
  float r = block_sum_256(total, tmp);
  if (t == 0) atomicAdd(out + b, -r);
}

__global__ __launch_bounds__(256) void k_attn(const float* __restrict__ z,
                                              const float* __restrict__ wq,
                                              const float* __restrict__ wk,
                                              float* __restrict__ out) {
  __shared__ float lds[8192];
  __shared__ float red[4];
  const int b = blockIdx.x >> 1, half = blockIdx.x & 1;
  const int t = threadIdx.x;
  const int lane = t & 63;
  const int w = __builtin_amdgcn_readfirstlane(t >> 6);
  const float4* zb4 = (const float4*)(z + (size_t)b * 16384);

  float qa[4][8], ka[4][8];
#pragma unroll
  for (int hh = 0; hh < 4; ++hh)
#pragma unroll
    for (int j = 0; j < 8; ++j) { qa[hh][j] = 0.f; ka[hh][j] = 0.f; }

  float4* lds4 = (float4*)lds;
  for (int dc = 0; dc < 2; ++dc) {
    __syncthreads();
    for (int i = t; i < 2048; i += 256) {
      int p = i >> 5, ld4 = i & 31;
      lds4[ld4 * 64 + (p ^ (ld4 & 7))] = zb4[p * 64 + dc * 32 + ld4];
    }
    __syncthreads();
#pragma unroll
    for (int hh = 0; hh < 4; ++hh) {
      int h = half * 4 + hh;
      const float* Wqb = wq + (size_t)h * 8192 + (size_t)(w * 8) * 256 + dc * 128;
      const float* Wkb = wk + (size_t)h * 8192 + (size_t)(w * 8) * 256 + dc * 128;
      for (int ld4 = 0; ld4 < 32; ++ld4) {
        float4 wv[8], kv[8];
#pragma unroll
        for (int j = 0; j < 8; ++j) {
          wv[j] = *(const float4*)(Wqb + j * 256 + ld4 * 4);
          kv[j] = *(const float4*)(Wkb + j * 256 + ld4 * 4);
        }
        float4 zv = lds4[ld4 * 64 + (lane ^ (ld4 & 7))];
#pragma unroll
        for (int j = 0; j < 8; ++j) {
          qa[hh][j] = fmaf(wv[j].x, zv.x, fmaf(wv[j].y, zv.y,
                      fmaf(wv[j].z, zv.z, fmaf(wv[j].w, zv.w, qa[hh][j]))));
          ka[hh][j] = fmaf(kv[j].x, zv.x, fmaf(kv[j].y, zv.y,
                      fmaf(kv[j].z, zv.z, fmaf(kv[j].w, zv.w, ka[hh][j]))));
        }
      }
    }
  }

  float* Qs = lds;
  float* Ks = lds + 2048;
  float lse = 0.f;
#pragma unroll
  for (int hh = 0; hh < 4; ++hh) {
    __syncthreads();
#pragma unroll
    for (int j = 0; j < 8; ++j) {
      Qs[(w * 8 + j) * 64 + lane] = qa[hh][j];
      Ks[(w * 8 + j) * 64 + lane] = ka[hh][j];
    }
    __syncthreads();
    float av[16];
#pragma unroll
    for (int mm = 0; mm < 16; ++mm) av[mm] = 0.f;
    for (int rr = 0; rr < 32; ++rr) {
      float kv = Ks[rr * 64 + lane];
      const float* qrow = &Qs[rr * 64 + w * 16];
      float4 q0 = *(const float4*)(qrow + 0);
      float4 q1 = *(const float4*)(qrow + 4);
      float4 q2 = *(const float4*)(qrow + 8);
      float4 q3 = *(const float4*)(qrow + 12);
      av[0]  = fmaf(q0.x, kv, av[0]);  av[1]  = fmaf(q0.y, kv, av[1]);
      av[2]  = fmaf(q0.z, kv, av[2]);  av[3]  = fmaf(q0.w, kv, av[3]);
      av[4]  = fmaf(q1.x, kv, av[4]);  av[5]  = fmaf(q1.y, kv, av[5]);
      av[6]  = fmaf(q1.z, kv, av[6]);  av[7]  = fmaf(q1.w, kv, av[7]);
      av[8]  = fmaf(q2.x, kv, av[8]);  av[9]  = fmaf(q2.y, kv, av[9]);
      av[10] = fmaf(q2.z, kv, av[10]); av[11] = fmaf(q2.w, kv, av[11]);
      av[12] = fmaf(q3.x, kv, av[12]); av[13] = fmaf(q3.y, kv, av[13]);
      av[14] = fmaf(q3.z, kv, av[14]); av[15] = fmaf(q3.w, kv, av[15]);
    }
#pragma unroll
    for (int mm = 0; mm < 16; ++mm) {
      float e = __expf(GAMMA * av[mm]);
#pragma unroll
      for (int off = 32; off; off >>= 1) e += __shfl_xor(e, off, 64);
      lse += __logf(e);
    }
  }
  if (lane == 0) red[w] = lse;
  __syncthreads();
  if (t == 0)
    atomicAdd(out + b, -(red[0] + red[1] + red[2] + red[3]) * (1.0f / GAMMA));
}

// ---------------------------------------------------------------------------
extern "C" void kernel_launch(void* const* d_in, const int* in_sizes, int n_in,
                              void* d_out, int out_size, void* d_ws,
                              size_t ws_size, hipStream_t stream) {
  (void)in_sizes; (void)n_in; (void)out_size;
  const float* x  = (const float*)d_in[0];
  const float* z  = (const float*)d_in[1];
  const float* ew = (const float*)d_in[2];
  const float* eb = (const float*)d_in[3];
  const float* vb = (const float*)d_in[4];
  const float* pb = (const float*)d_in[5];
  const float* mw = (const float*)d_in[6];
  const float* wq = (const float*)d_in[7];
  const float* wk = (const float*)d_in[8];
  float* out = (float*)d_out;

  const size_t MT_B = (size_t)1024 * 256 * 2;   // 512 KB mtf
  const size_t WC_B = (size_t)512 * 256 * 2;    // 256 KB wcf
  const size_t EW_B = (size_t)96 * 64 * 8 * 2;  // 96 KB ewt
  const size_t FULL = MT_B + WC_B + EW_B;       // ~0.86 MB

  ushort* mtf = (ushort*)d_ws;
  ushort* wcf = (ushort*)((char*)d_ws + MT_B);
  ushort* ewt = (ushort*)((char*)d_ws + MT_B + WC_B);

  if (ws_size >= FULL) {
    k_cvt_weights_v4<<<216, 256, 0, stream>>>(wq, wk, ew, mw, wcf, ewt, mtf);
    k_omega<<<1024, 256, 0, stream>>>(x, z, eb, vb, pb, ewt, mtf, wcf, out);
  } else {
    k_xz  <<<1024, 256, 0, stream>>>(x, z, vb, eb, pb, out);
    k_enc <<<1024, 256, 0, stream>>>(x, z, ew, out);
    k_mem <<<4096, 256, 0, stream>>>(z, mw, out);
    k_attn<<<2048, 256, 0, stream>>>(z, wq, wk, out);
  }
}

// Round 10
// 221.590 us; speedup vs baseline: 1.3576x; 1.1792x over previous
//
#include <hip/hip_runtime.h>
#include <hip/hip_bf16.h>

#define GAMMA 0.25f

// Shapes: B=1024, C=3, H=64, D=256, NP=64 (8x8 grid of 8x8 patches),
//         M=1024, NH=8, R=32, P=8.  fp32 in/out.  out[b] = quad - coupling.
//
// R10: revert to the R5 split (k_mega verbatim, 78us measured; k_enc_v5
// verbatim, ~65-70us) and fix the HIDDEN ~70us kernel: k_cvt_weights.
// Cross-round accounting shows ~70-75us unattributed in R5/R8/R9 — the
// cvt kernel's mtf transpose does 8 scalar 4B loads at 4KB stride/thread
// on a 216-block grid (no TLP to hide L2 latency).  v5 cvt: mtf via
// LDS-staged transpose (coalesced float4 reads of mw, coalesced 16B/lane
// fragment writes), wcf via 2x float4 loads.  R9 lesson recorded: fusing
// enc into mega cost VGPR 132 + 64KB LDS -> 11.5% occupancy, net loss.

typedef __attribute__((ext_vector_type(8))) short short8;  // 8 bf16 (4 VGPRs)
typedef __attribute__((ext_vector_type(4))) float f32x4;   // 4 fp32 acc

__device__ __forceinline__ float dot4(float4 a, float4 b) {
  return fmaf(a.x, b.x, fmaf(a.y, b.y, fmaf(a.z, b.z, a.w * b.w)));
}

__device__ __forceinline__ void fma4(float4& a, float s, float4 w) {
  a.x = fmaf(s, w.x, a.x); a.y = fmaf(s, w.y, a.y);
  a.z = fmaf(s, w.z, a.z); a.w = fmaf(s, w.w, a.w);
}

__device__ __forceinline__ ushort f2bf(float f) {
  __hip_bfloat16 h = __float2bfloat16(f);  // RNE
  return *reinterpret_cast<ushort*>(&h);
}

__device__ __forceinline__ float bf2f(ushort u) {
  union { unsigned int i; float f; } v;
  v.i = ((unsigned int)u) << 16;
  return v.f;
}

// 256-thread block sum; result valid on all threads.
__device__ __forceinline__ float block_sum_256(float v, float* tmp) {
#pragma unroll
  for (int off = 32; off; off >>= 1) v += __shfl_down(v, off, 64);
  int w = threadIdx.x >> 6;
  if ((threadIdx.x & 63) == 0) tmp[w] = v;
  __syncthreads();
  return tmp[0] + tmp[1] + tmp[2] + tmp[3];
}

// ---------------------------------------------------------------------------
// Weight conversion v5 — COALESCED.  Grid 120 blocks:
// [0,64)    wcf: frag=ctg*8+kc: Wcat cols; per-lane 2x float4 (32B contig).
// [64,88)   ewt: frag=ks*12+ct (small, strided scalar — 96KB total, cheap).
// [88,120)  mtf via LDS transpose: block (kc,mg) reads mw[32k x 256m] fp32
//           coalesced, stages bf16 in padded LDS, writes 16 frags coalesced.
// Fragment = contiguous [l][8] 1KB wave-block (layouts identical to v4).
// ---------------------------------------------------------------------------
__global__ __launch_bounds__(256) void k_cvt_weights_v5(
    const float* __restrict__ wq, const float* __restrict__ wk,
    const float* __restrict__ ew, const float* __restrict__ mw,
    ushort* __restrict__ wcf, ushort* __restrict__ ewt,
    ushort* __restrict__ mtf) {
  int bid = blockIdx.x, t = threadIdx.x;
  if (bid < 64) {
    int tid = bid * 256 + t;  // 0..16383
    int frag = tid >> 6, l = tid & 63;
    int ctg = frag >> 3, kc = frag & 7;
    int col = ctg * 16 + (l & 15);
    int h = col >> 6, qk = (col >> 5) & 1, rr = col & 31;
    int k0 = kc * 32 + (l >> 4) * 8;
    const float* s = (qk ? wk : wq) + ((size_t)h * 32 + rr) * 256 + k0;
    float4 u = *(const float4*)s;
    float4 v = *(const float4*)(s + 4);
    ushort o[8];
    o[0] = f2bf(u.x); o[1] = f2bf(u.y); o[2] = f2bf(u.z); o[3] = f2bf(u.w);
    o[4] = f2bf(v.x); o[5] = f2bf(v.y); o[6] = f2bf(v.z); o[7] = f2bf(v.w);
    *(ushort4*)(wcf + (size_t)tid * 8) = *(ushort4*)&o[0];
    *(ushort4*)(wcf + (size_t)tid * 8 + 4) = *(ushort4*)&o[4];
  } else if (bid < 88) {
    int tid = (bid - 64) * 256 + t;  // 0..6143
    int frag = tid >> 6, l = tid & 63;
    int ks = frag / 12, ct = frag % 12;
    const float* s = ew + (size_t)(ks * 32 + (l >> 4) * 8) * 192 +
                     ct * 16 + (l & 15);
    ushort o[8];
#pragma unroll
    for (int i = 0; i < 8; ++i) o[i] = f2bf(s[(size_t)i * 192]);
    *(ushort4*)(ewt + (size_t)tid * 8) = *(ushort4*)&o[0];
    *(ushort4*)(ewt + (size_t)tid * 8 + 4) = *(ushort4*)&o[4];
  } else {
    // mtf: block handles (kc = (bid-88)>>2, mg = (bid-88)&3).
    __shared__ ushort tile[32][264];  // [k_loc][m_loc], +8 pad
    int bid2 = bid - 88;
    int kc = bid2 >> 2, mg = bid2 & 3;
    // Coalesced read: 2048 float4s; thread t iter j -> idx = t + j*256.
#pragma unroll
    for (int j = 0; j < 8; ++j) {
      int idx = t + j * 256;
      int kl = idx >> 6, m4 = idx & 63;
      float4 v = *(const float4*)(mw + (size_t)(kc * 32 + kl) * 1024 +
                                  mg * 256 + m4 * 4);
      ushort* dst = &tile[kl][m4 * 4];
      dst[0] = f2bf(v.x); dst[1] = f2bf(v.y);
      dst[2] = f2bf(v.z); dst[3] = f2bf(v.w);
    }
    __syncthreads();
    // Emit 16 fragments (C = mg*16+fl, kc): 1024 lane-entries = 256 thr x 4.
#pragma unroll
    for (int j = 0; j < 4; ++j) {
      int e = t + j * 256;
      int fl = e >> 6, l2 = e & 63;
      int frag = (mg * 16 + fl) * 8 + kc;
      int m_loc = fl * 16 + (l2 & 15);
      ushort o[8];
#pragma unroll
      for (int i = 0; i < 8; ++i) o[i] = tile[(l2 >> 4) * 8 + i][m_loc];
      *(ushort4*)(mtf + ((size_t)frag * 64 + l2) * 8) = *(ushort4*)&o[0];
      *(ushort4*)(mtf + ((size_t)frag * 64 + l2) * 8 + 4) = *(ushort4*)&o[4];
    }
  }
}

// ---------------------------------------------------------------------------
// Mega-kernel (R5 VERBATIM, measured 78us): quad_z - phi_bias - phi_pos -
// phi_mem - phi_att per b.  LDS: SL[0,16384) zf frag-ordered, SL[16384,)
// dstg XOR-swizzled [64][256].  64KB -> 2 blocks/CU.
// ---------------------------------------------------------------------------
__global__ __launch_bounds__(256) void k_mega(
    const float* __restrict__ z, const float* __restrict__ eb,
    const float* __restrict__ pb, const ushort* __restrict__ mtf,
    const ushort* __restrict__ wcf, float* __restrict__ out) {
  __shared__ ushort SL[32768];  // 64 KB
  const int t = threadIdx.x, l = t & 63, w = t >> 6;
  const int b = blockIdx.x;
  const int q = l >> 4, m = l & 15;
  float s = 0.f;

  // ---- Phase 0: z fp32 -> quad_z - phi_bias - phi_pos; zf (bf16) to LDS.
  {
    const float4* zb4 = (const float4*)(z + (size_t)b * 16384);
    const float4* pb4 = (const float4*)pb;
    const float4* eb4 = (const float4*)eb;
#pragma unroll
    for (int n = 0; n < 16; ++n) {
      int i = t + n * 256;
      float4 zv = zb4[i];
      float4 pv = pb4[i];
      float4 ev = eb4[i & 63];
      float4 c;
      c.x = pv.x + ev.x; c.y = pv.y + ev.y;
      c.z = pv.z + ev.z; c.w = pv.w + ev.w;
      s += 0.5f * dot4(zv, zv) - dot4(zv, c);
      int p = i >> 6, d4 = i & 63;
      int ks = d4 >> 3, sub = (d4 & 7) >> 1, e0 = (d4 & 1) * 4;
      int li = (p & 15) + sub * 16;
      ushort4 o;
      o.x = f2bf(zv.x); o.y = f2bf(zv.y); o.z = f2bf(zv.z); o.w = f2bf(zv.w);
      *(ushort4*)(SL + (size_t)(((p >> 4) * 8 + ks) * 64 + li) * 8 + e0) = o;
    }
  }
  __syncthreads();

  // ---- Phase 1: phi_mem (4 ct chunks; B from L2 mtf).
#pragma unroll 1
  for (int ct = 0; ct < 4; ++ct) {
    const ushort* Bb = mtf + ((size_t)(ct * 16 + w * 4) * 8) * 512 +
                       (size_t)l * 8;
    short8 fb[2][4];
#pragma unroll
    for (int c = 0; c < 4; ++c) fb[0][c] = *(const short8*)(Bb + (c * 8 + 0) * 512);
#pragma unroll
    for (int c = 0; c < 4; ++c) fb[1][c] = *(const short8*)(Bb + (c * 8 + 1) * 512);

    f32x4 acc[4][4];
#pragma unroll
    for (int r = 0; r < 4; ++r)
#pragma unroll
      for (int c = 0; c < 4; ++c) acc[r][c] = f32x4{0.f, 0.f, 0.f, 0.f};

#pragma unroll
    for (int kc = 0; kc < 8; ++kc) {
      const int cur = kc & 1;
      short8 a4[4];
#pragma unroll
      for (int r = 0; r < 4; ++r)
        a4[r] = *(const short8*)(SL + (size_t)((r * 8 + kc) * 64 + l) * 8);
#pragma unroll
      for (int r = 0; r < 4; ++r)
#pragma unroll
        for (int c = 0; c < 4; ++c)
          acc[r][c] = __builtin_amdgcn_mfma_f32_16x16x32_bf16(a4[r], fb[cur][c],
                                                              acc[r][c], 0, 0, 0);
      if (kc < 6) {
#pragma unroll
        for (int c = 0; c < 4; ++c)
          fb[cur][c] = *(const short8*)(Bb + (c * 8 + kc + 2) * 512);
      }
    }
#pragma unroll
    for (int r = 0; r < 4; ++r)
#pragma unroll
      for (int c = 0; c < 4; ++c)
#pragma unroll
        for (int e = 0; e < 4; ++e) {
          float rr = fmaxf(acc[r][c][e], 0.f);
          s -= rr * rr;
        }
  }

  // ---- Phase 2: phi_att (both halves; dstg XOR-swizzled).
  float part = 0.f;
  char* dstg = (char*)(SL + 16384);
#pragma unroll 1
  for (int half = 0; half < 2; ++half) {
    const ushort* Bb = wcf + ((size_t)((half * 16 + w * 4) * 8)) * 512 +
                       (size_t)l * 8;
    short8 fb[2][4];
#pragma unroll
    for (int c = 0; c < 4; ++c) fb[0][c] = *(const short8*)(Bb + (c * 8 + 0) * 512);
#pragma unroll
    for (int c = 0; c < 4; ++c) fb[1][c] = *(const short8*)(Bb + (c * 8 + 1) * 512);

    f32x4 acc[4][4];
#pragma unroll
    for (int r = 0; r < 4; ++r)
#pragma unroll
      for (int c = 0; c < 4; ++c) acc[r][c] = f32x4{0.f, 0.f, 0.f, 0.f};

#pragma unroll
    for (int kc = 0; kc < 8; ++kc) {
      const int cur = kc & 1;
      short8 a4[4];
#pragma unroll
      for (int r = 0; r < 4; ++r)
        a4[r] = *(const short8*)(SL + (size_t)((r * 8 + kc) * 64 + l) * 8);
#pragma unroll
      for (int r = 0; r < 4; ++r)
#pragma unroll
        for (int c = 0; c < 4; ++c)
          acc[r][c] = __builtin_amdgcn_mfma_f32_16x16x32_bf16(a4[r], fb[cur][c],
                                                              acc[r][c], 0, 0, 0);
      if (kc < 6) {
#pragma unroll
        for (int c = 0; c < 4; ++c)
          fb[cur][c] = *(const short8*)(Bb + (c * 8 + kc + 2) * 512);
      }
    }

    // D (row = 16rt+4q+reg, col = (4w+c)*16+m) -> bf16 -> dstg, XOR-swizzled.
#pragma unroll
    for (int rt = 0; rt < 4; ++rt)
#pragma unroll
      for (int c = 0; c < 4; ++c)
#pragma unroll
        for (int reg = 0; reg < 4; ++reg) {
          int row = 16 * rt + 4 * q + reg;
          int col = (4 * w + c) * 16 + m;
          int ba = ((row * 256 + col) * 2) ^ ((row & 7) << 4);
          *(ushort*)(dstg + ba) = f2bf(acc[rt][c][reg]);
        }
    __syncthreads();

    // Phase C: per head hh, Q rows 16w+m, K tiles nt; cols hh*64 (+32 for K).
#pragma unroll
    for (int hh = 0; hh < 4; ++hh) {
      int rowq = 16 * w + m;
      short8 qa = *(const short8*)(
          dstg + (((rowq * 256 + hh * 64 + q * 8) * 2) ^ ((rowq & 7) << 4)));
      f32x4 a2[4];
#pragma unroll
      for (int nt = 0; nt < 4; ++nt) {
        int rowk = 16 * nt + m;
        short8 kb = *(const short8*)(
            dstg + (((rowk * 256 + hh * 64 + 32 + q * 8) * 2) ^ ((rowk & 7) << 4)));
        a2[nt] = __builtin_amdgcn_mfma_f32_16x16x32_bf16(
            qa, kb, f32x4{0.f, 0.f, 0.f, 0.f}, 0, 0, 0);
      }
#pragma unroll
      for (int reg = 0; reg < 4; ++reg) {
        float e = __expf(GAMMA * a2[0][reg]) + __expf(GAMMA * a2[1][reg]) +
                  __expf(GAMMA * a2[2][reg]) + __expf(GAMMA * a2[3][reg]);
        e += __shfl_xor(e, 1, 64);
        e += __shfl_xor(e, 2, 64);
        e += __shfl_xor(e, 4, 64);
        e += __shfl_xor(e, 8, 64);
        part += (m == 0) ? __logf(e) : 0.f;  // one log per row 16w+4q+reg
      }
    }
    __syncthreads();  // dstg reads done before next half's writes
  }
  s -= part * (1.0f / GAMMA);

  float r = block_sum_256(s, (float*)SL);  // zf dead; reuse as tmp
  if (t == 0) out[b] = r;
}

// ---------------------------------------------------------------------------
// Kernel: quad_x - phi_vis - phi_enc (R5 enc_v5 VERBATIM).
// ---------------------------------------------------------------------------
__global__ __launch_bounds__(256) void k_enc_v5(
    const float* __restrict__ x, const float* __restrict__ vb,
    const float* __restrict__ z, const ushort* __restrict__ ewt,
    float* __restrict__ out) {
  __shared__ ushort xs[12288];      // 24 KB: x[b] bf16, NCHW layout
  __shared__ ushort ebuf[2][6144];  // 2 x 12 KB: ewt ks-chunk double buffer
  __shared__ float tmp[4];
  const int b = blockIdx.x, t = threadIdx.x, l = t & 63, w = t >> 6;
  const int q = l >> 4, m = l & 15;

  // z A-frags from fp32 (L3-warm after k_mega); RNE cvt == bf16 path.
  const float* Zr = z + (size_t)b * 16384 + (size_t)(16 * w + m) * 256 + q * 8;
  short8 a[8];
#pragma unroll
  for (int ks = 0; ks < 8; ++ks) {
    float4 u = *(const float4*)(Zr + ks * 32);
    float4 v = *(const float4*)(Zr + ks * 32 + 4);
    ushort o[8];
    o[0] = f2bf(u.x); o[1] = f2bf(u.y); o[2] = f2bf(u.z); o[3] = f2bf(u.w);
    o[4] = f2bf(v.x); o[5] = f2bf(v.y); o[6] = f2bf(v.z); o[7] = f2bf(v.w);
    a[ks] = *(short8*)o;
  }

  // chunk-0 staging loads (in flight during x staging)
  short8 st[3];
#pragma unroll
  for (int i = 0; i < 3; ++i)
    st[i] = *(const short8*)(ewt + (size_t)(t + i * 256) * 8);

  // Stage x -> bf16 LDS; accumulate quad_x - phi_vis.
  const float4* xb = (const float4*)(x + (size_t)b * 12288);
  const float4* vb4 = (const float4*)vb;
  ushort4* xs4 = (ushort4*)xs;
  float s = 0.f;
  for (int i = t; i < 3072; i += 256) {
    float4 xv = xb[i];
    float4 bv = vb4[i];
    s += 0.5f * dot4(xv, xv) - dot4(bv, xv);
    ushort4 o;
    o.x = f2bf(xv.x); o.y = f2bf(xv.y); o.z = f2bf(xv.z); o.w = f2bf(xv.w);
    xs4[i] = o;
  }
#pragma unroll
  for (int i = 0; i < 3; ++i)
    *(short8*)(ebuf[0] + (size_t)(t + i * 256) * 8) = st[i];
  __syncthreads();

  f32x4 acc[12];
#pragma unroll
  for (int ct = 0; ct < 12; ++ct) acc[ct] = f32x4{0.f, 0.f, 0.f, 0.f};

#pragma unroll
  for (int ks = 0; ks < 8; ++ks) {
    const int cur = ks & 1;
    if (ks < 7) {
#pragma unroll
      for (int i = 0; i < 3; ++i)
        st[i] = *(const short8*)(ewt + (size_t)(ks + 1) * 6144 +
                                 (size_t)(t + i * 256) * 8);
    }
#pragma unroll
    for (int ct = 0; ct < 12; ++ct) {
      short8 bv = *(const short8*)(ebuf[cur] + (size_t)(ct * 64 + l) * 8);
      acc[ct] = __builtin_amdgcn_mfma_f32_16x16x32_bf16(a[ks], bv, acc[ct], 0, 0, 0);
    }
    if (ks < 7) {
#pragma unroll
      for (int i = 0; i < 3; ++i)
        *(short8*)(ebuf[cur ^ 1] + (size_t)(t + i * 256) * 8) = st[i];
    }
    __syncthreads();
  }

  // Epilogue: D element (row p=16w+4q+reg, col k=16ct+m) * x[p,k] from LDS.
#pragma unroll
  for (int ct = 0; ct < 12; ++ct) {
#pragma unroll
    for (int reg = 0; reg < 4; ++reg) {
      const int p = 16 * w + 4 * q + reg, gi = p >> 3, gj = p & 7;
      const int k = ct * 16 + m, c = k >> 6, r2 = k & 63;
      const int ii = r2 >> 3, jj = r2 & 7;
      s -= acc[ct][reg] * bf2f(xs[c * 4096 + (gi * 8 + ii) * 64 + gj * 8 + jj]);
    }
  }
  float r = block_sum_256(s, tmp);
  if (t == 0) atomicAdd(out + b, r);  // += quad_x - phi_vis - phi_enc
}

// ---------------------------------------------------------------------------
// Fallback kernels (no-workspace tier).
// ---------------------------------------------------------------------------
__global__ __launch_bounds__(256) void k_xz(const float* __restrict__ x,
                                            const float* __restrict__ z,
                                            const float* __restrict__ vb,
                                            const float* __restrict__ eb,
                                            const float* __restrict__ pb,
                                            float* __restrict__ out) {
  __shared__ float tmp[4];
  int b = blockIdx.x, t = threadIdx.x;
  const float4* xb = (const float4*)(x + (size_t)b * 12288);
  const float4* vb4 = (const float4*)vb;
  float s = 0.f;
  for (int i = t; i < 3072; i += 256) {
    float4 xv = xb[i];
    float4 bv = vb4[i];
    s += 0.5f * dot4(xv, xv) - dot4(bv, xv);
  }
  const float4* zb = (const float4*)(z + (size_t)b * 16384);
  const float4* pb4 = (const float4*)pb;
  const float4* eb4 = (const float4*)eb;
  for (int i = t; i < 4096; i += 256) {
    float4 zv = zb[i];
    float4 pv = pb4[i];
    float4 ev = eb4[i & 63];
    float4 c;
    c.x = pv.x + ev.x; c.y = pv.y + ev.y; c.z = pv.z + ev.z; c.w = pv.w + ev.w;
    s += 0.5f * dot4(zv, zv) - dot4(zv, c);
  }
  float r = block_sum_256(s, tmp);
  if (t == 0) out[b] = r;
}

__global__ __launch_bounds__(256) void k_enc(const float* __restrict__ x,
                                             const float* __restrict__ z,
                                             const float* __restrict__ ew,
                                             float* __restrict__ out) {
  __shared__ float xs[12288];
  __shared__ float tmp[4];
  int b = blockIdx.x, t = threadIdx.x;
  const float4* xb4 = (const float4*)(x + (size_t)b * 12288);
  for (int i = t; i < 3072; i += 256) ((float4*)xs)[i] = xb4[i];
  __syncthreads();

  float acc[64];
#pragma unroll
  for (int p = 0; p < 64; ++p) acc[p] = 0.f;

  for (int k4 = 0; k4 < 48; ++k4) {
    float4 wv = *(const float4*)(ew + (size_t)t * 192 + k4 * 4);
    int c = k4 >> 4;
    int ii = (k4 >> 1) & 7;
    int jh = (k4 & 1) * 4;
    const float* base = xs + c * 4096 + ii * 64 + jh;
#pragma unroll
    for (int p = 0; p < 64; ++p) {
      float4 pv = *(const float4*)(base + (p >> 3) * 512 + (p & 7) * 8);
      acc[p] = fmaf(wv.x, pv.x,
               fmaf(wv.y, pv.y, fmaf(wv.z, pv.z, fmaf(wv.w, pv.w, acc[p]))));
    }
  }
  const float* zb = z + (size_t)b * 16384;
  float s = 0.f;
#pragma unroll
  for (int p = 0; p < 64; ++p) s += acc[p] * zb[p * 256 + t];
  float r = block_sum_256(s, tmp);
  if (t == 0) atomicAdd(out + b, -r);
}

__global__ __launch_bounds__(256) void k_mem(const float* __restrict__ z,
                                             const float* __restrict__ mw,
                                             float* __restrict__ out) {
  __shared__ float zs[16 * 256];
  __shared__ float tmp[4];
  int b = blockIdx.x >> 2, pt = blockIdx.x & 3, t = threadIdx.x;
  const float4* zb4 = (const float4*)(z + (size_t)b * 16384 + pt * 4096);
  for (int i = t; i < 1024; i += 256) ((float4*)zs)[i] = zb4[i];
  __syncthreads();

  const float4* m4 = (const float4*)mw;
  float4 acc[16];
#pragma unroll
  for (int pp = 0; pp < 16; ++pp) acc[pp] = make_float4(0.f, 0.f, 0.f, 0.f);

#pragma unroll 2
  for (int k4 = 0; k4 < 64; ++k4) {
    float4 w0 = m4[(4 * k4 + 0) * 256 + t];
    float4 w1 = m4[(4 * k4 + 1) * 256 + t];
    float4 w2 = m4[(4 * k4 + 2) * 256 + t];
    float4 w3 = m4[(4 * k4 + 3) * 256 + t];
#pragma unroll
    for (int pp = 0; pp < 16; ++pp) {
      float4 zv = *(const float4*)&zs[pp * 256 + k4 * 4];
      fma4(acc[pp], zv.x, w0);
      fma4(acc[pp], zv.y, w1);
      fma4(acc[pp], zv.z, w2);
      fma4(acc[pp], zv.w, w3);
    }
  }
  float total = 0.f;
#pragma unroll
  for (int pp = 0; pp < 16; ++pp) {
    float r;
    r = fmaxf(acc[pp].x, 0.f); total = fmaf(r, r, total);
    r = fmaxf(acc[pp].y, 0.f); total = fmaf(r, r, total);
    r = fmaxf(acc[pp].z, 0.f); total = fmaf(r, r, total);
    r = fmaxf(acc[pp].w, 0.f); total = fmaf(r, r, total);
  }
  float r = block_sum_256(total, tmp);
  if (t == 0) atomicAdd(out + b, -r);
}

__global__ __launch_bounds__(256) void k_attn(const float* __restrict__ z,
                                              const float* __restrict__ wq,
                                              const float* __restrict__ wk,
                                              float* __restrict__ out) {
  __shared__ float lds[8192];
  __shared__ float red[4];
  const int b = blockIdx.x >> 1, half = blockIdx.x & 1;
  const int t = threadIdx.x;
  const int lane = t & 63;
  const int w = __builtin_amdgcn_readfirstlane(t >> 6);
  const float4* zb4 = (const float4*)(z + (size_t)b * 16384);

  float qa[4][8], ka[4][8];
#pragma unroll
  for (int hh = 0; hh < 4; ++hh)
#pragma unroll
    for (int j = 0; j < 8; ++j) { qa[hh][j] = 0.f; ka[hh][j] = 0.f; }

  float4* lds4 = (float4*)lds;
  for (int dc = 0; dc < 2; ++dc) {
    __syncthreads();
    for (int i = t; i < 2048; i += 256) {
      int p = i >> 5, ld4 = i & 31;
      lds4[ld4 * 64 + (p ^ (ld4 & 7))] = zb4[p * 64 + dc * 32 + ld4];
    }
    __syncthreads();
#pragma unroll
    for (int hh = 0; hh < 4; ++hh) {
      int h = half * 4 + hh;
      const float* Wqb = wq + (size_t)h * 8192 + (size_t)(w * 8) * 256 + dc * 128;
      const float* Wkb = wk + (size_t)h * 8192 + (size_t)(w * 8) * 256 + dc * 128;
      for (int ld4 = 0; ld4 < 32; ++ld4) {
        float4 wv[8], kv[8];
#pragma unroll
        for (int j = 0; j < 8; ++j) {
          wv[j] = *(const float4*)(Wqb + j * 256 + ld4 * 4);
          kv[j] = *(const float4*)(Wkb + j * 256 + ld4 * 4);
        }
        float4 zv = lds4[ld4 * 64 + (lane ^ (ld4 & 7))];
#pragma unroll
        for (int j = 0; j < 8; ++j) {
          qa[hh][j] = fmaf(wv[j].x, zv.x, fmaf(wv[j].y, zv.y,
                      fmaf(wv[j].z, zv.z, fmaf(wv[j].w, zv.w, qa[hh][j]))));
          ka[hh][j] = fmaf(kv[j].x, zv.x, fmaf(kv[j].y, zv.y,
                      fmaf(kv[j].z, zv.z, fmaf(kv[j].w, zv.w, ka[hh][j]))));
        }
      }
    }
  }

  float* Qs = lds;
  float* Ks = lds + 2048;
  float lse = 0.f;
#pragma unroll
  for (int hh = 0; hh < 4; ++hh) {
    __syncthreads();
#pragma unroll
    for (int j = 0; j < 8; ++j) {
      Qs[(w * 8 + j) * 64 + lane] = qa[hh][j];
      Ks[(w * 8 + j) * 64 + lane] = ka[hh][j];
    }
    __syncthreads();
    float av[16];
#pragma unroll
    for (int mm = 0; mm < 16; ++mm) av[mm] = 0.f;
    for (int rr = 0; rr < 32; ++rr) {
      float kv = Ks[rr * 64 + lane];
      const float* qrow = &Qs[rr * 64 + w * 16];
      float4 q0 = *(const float4*)(qrow + 0);
      float4 q1 = *(const float4*)(qrow + 4);
      float4 q2 = *(const float4*)(qrow + 8);
      float4 q3 = *(const float4*)(qrow + 12);
      av[0]  = fmaf(q0.x, kv, av[0]);  av[1]  = fmaf(q0.y, kv, av[1]);
      av[2]  = fmaf(q0.z, kv, av[2]);  av[3]  = fmaf(q0.w, kv, av[3]);
      av[4]  = fmaf(q1.x, kv, av[4]);  av[5]  = fmaf(q1.y, kv, av[5]);
      av[6]  = fmaf(q1.z, kv, av[6]);  av[7]  = fmaf(q1.w, kv, av[7]);
      av[8]  = fmaf(q2.x, kv, av[8]);  av[9]  = fmaf(q2.y, kv, av[9]);
      av[10] = fmaf(q2.z, kv, av[10]); av[11] = fmaf(q2.w, kv, av[11]);
      av[12] = fmaf(q3.x, kv, av[12]); av[13] = fmaf(q3.y, kv, av[13]);
      av[14] = fmaf(q3.z, kv, av[14]); av[15] = fmaf(q3.w, kv, av[15]);
    }
#pragma unroll
    for (int mm = 0; mm < 16; ++mm) {
      float e = __expf(GAMMA * av[mm]);
#pragma unroll
      for (int off = 32; off; off >>= 1) e += __shfl_xor(e, off, 64);
      lse += __logf(e);
    }
  }
  if (lane == 0) red[w] = lse;
  __syncthreads();
  if (t == 0)
    atomicAdd(out + b, -(red[0] + red[1] + red[2] + red[3]) * (1.0f / GAMMA));
}

// ---------------------------------------------------------------------------
extern "C" void kernel_launch(void* const* d_in, const int* in_sizes, int n_in,
                              void* d_out, int out_size, void* d_ws,
                              size_t ws_size, hipStream_t stream) {
  (void)in_sizes; (void)n_in; (void)out_size;
  const float* x  = (const float*)d_in[0];
  const float* z  = (const float*)d_in[1];
  const float* ew = (const float*)d_in[2];
  const float* eb = (const float*)d_in[3];
  const float* vb = (const float*)d_in[4];
  const float* pb = (const float*)d_in[5];
  const float* mw = (const float*)d_in[6];
  const float* wq = (const float*)d_in[7];
  const float* wk = (const float*)d_in[8];
  float* out = (float*)d_out;

  const size_t MT_B = (size_t)1024 * 256 * 2;   // 512 KB mtf
  const size_t WC_B = (size_t)512 * 256 * 2;    // 256 KB wcf
  const size_t EW_B = (size_t)96 * 64 * 8 * 2;  // 96 KB ewt
  const size_t FULL = MT_B + WC_B + EW_B;       // ~0.86 MB

  ushort* mtf = (ushort*)d_ws;
  ushort* wcf = (ushort*)((char*)d_ws + MT_B);
  ushort* ewt = (ushort*)((char*)d_ws + MT_B + WC_B);

  if (ws_size >= FULL) {
    k_cvt_weights_v5<<<120, 256, 0, stream>>>(wq, wk, ew, mw, wcf, ewt, mtf);
    k_mega  <<<1024, 256, 0, stream>>>(z, eb, pb, mtf, wcf, out);
    k_enc_v5<<<1024, 256, 0, stream>>>(x, vb, z, ewt, out);
  } else {
    k_xz  <<<1024, 256, 0, stream>>>(x, z, vb, eb, pb, out);
    k_enc <<<1024, 256, 0, stream>>>(x, z, ew, out);
    k_mem <<<4096, 256, 0, stream>>>(z, mw, out);
    k_attn<<<2048, 256, 0, stream>>>(z, wq, wk, out);
  }
}